// Round 19
// baseline (271.071 us; speedup 1.0000x reference)
//
#include <hip/hip_runtime.h>

#define DIM 256
#define NLr 16384
#define NGr 32768
#define NDr 8192
#define NE  262144
#define PADNE 524288   // padded srcw stride: NE + 8*max_n
#define HSTRIDE 32772  // poffs/pends per-relation stride (16B-aligned)

typedef short bf16x8 __attribute__((ext_vector_type(8)));
typedef float f32x4 __attribute__((ext_vector_type(4)));
typedef float f32x2 __attribute__((ext_vector_type(2)));
typedef unsigned u32x4 __attribute__((ext_vector_type(4)));

__device__ __forceinline__ unsigned short f2bf(float f) {
  unsigned int u = __builtin_bit_cast(unsigned int, f);
  u += 0x7fffu + ((u >> 16) & 1u);
  return (unsigned short)(u >> 16);
}
__device__ __forceinline__ float bf2f(unsigned short b) {
  return __builtin_bit_cast(float, ((unsigned int)b) << 16);
}
__device__ __forceinline__ float bfhi(unsigned int u) {
  return __builtin_bit_cast(float, u & 0xffff0000u);
}

struct NTab { int n[6]; };
struct PrepTab { const float* wsrc[9]; const int* dst[6]; int shift[6];
                 const float* apack[6]; };
struct PTab { const int* src[6]; const int* dst[6]; const float* w[6]; int shift[6]; };
struct TTy { const float* h[3]; unsigned char* hpA[3]; unsigned char* hpB[3];
             const unsigned short* wA[3]; const unsigned short* wB[3]; int cum[4]; };
struct GATab { const unsigned char* hpA[3]; const unsigned char* hpB[3];
               const unsigned* swA[3]; const unsigned* swB[3];
               const int* poA[3]; const int* peA[3];
               const int* poB[3]; const int* peB[3];
               const f32x2* A1p[3]; const f32x2* A2p[3];
               unsigned short* agg[3]; int cum[4]; };
struct FTab { const float* h[3]; const unsigned short* agg[3];
              const unsigned short* wbf[3]; const float* gm[3]; const float* bt[3];
              float* out[3]; int cum[4]; };

// ---- merged prep: [0,2304) weight conv; [2304,3840) coarse hist; [3840,3846) A-pack ----
__global__ __launch_bounds__(256) void prep_kernel(PrepTab Q, unsigned short* __restrict__ wbf,
                                                   int* __restrict__ chist,
                                                   f32x2* __restrict__ apk) {
  const int bid = blockIdx.x, tid = threadIdx.x;
  __shared__ int h[64];
  if (bid < 2304) {
    int m = bid >> 8;
    int i = (bid & 255) * 256 + tid;
    wbf[m * 65536 + i] = f2bf(Q.wsrc[m][i]);
  } else if (bid < 3840) {
    int b2 = bid - 2304;
    int r = b2 >> 8;          // 256 blocks per relation, 1024 edges each
    int blk = b2 & 255;
    if (tid < 64) h[tid] = 0;
    __syncthreads();
    const int* dp = Q.dst[r] + blk * 1024;
    const int sh = Q.shift[r];
#pragma unroll
    for (int k = 0; k < 4; ++k) atomicAdd(&h[dp[k * 256 + tid] >> sh], 1);
    __syncthreads();
    if (tid < 64) { int c = h[tid]; if (c) atomicAdd(&chist[r * 64 + tid], c); }
  } else {
    // pack A[4][256] -> head-pair f32x2 [2][256]: apk[k][p][d] = {A[2p][d], A[2p+1][d]}
    int k = bid - 3840;
    const float* A = Q.apack[k];
    f32x2* dst = apk + (size_t)k * 512;
    dst[tid]       = (f32x2){A[0 * 256 + tid], A[1 * 256 + tid]};
    dst[256 + tid] = (f32x2){A[2 * 256 + tid], A[3 * 256 + tid]};
  }
}

// ---- tiny coarse scan: ccur (partA cursor), cbase (tmp windows), pbase (padded srcw) ----
__global__ void scan384_kernel(const int* __restrict__ chist, int* __restrict__ ccur,
                               int* __restrict__ cbase, int* __restrict__ pbase, NTab N) {
  int r = threadIdx.x;
  if (r < 6) {
    int off = 0, offp = 0;
    int s8 = (N.n[r] >> 6) * 8;   // per-window pad slack
    for (int b = 0; b < 64; ++b) {
      ccur[r * 64 + b] = off;
      cbase[r * 65 + b] = off;
      pbase[r * 65 + b] = offp;
      off += chist[r * 64 + b];
      offp += chist[r * 64 + b] + s8;
    }
    cbase[r * 65 + 64] = off;  // == NE
  }
}

// ---- partition pass A: coarse 64-bucket partition into tmp (dst, packed) ----
__global__ __launch_bounds__(256) void partA6_kernel(PTab P, int* __restrict__ ccur,
                                                     int2* __restrict__ tmp) {
  int r = blockIdx.y;
  const int tid = threadIdx.x;
  __shared__ int hist[64], lbase[64], lcur[64];
  if (tid < 64) { hist[tid] = 0; lcur[tid] = 0; }
  __syncthreads();
  const int ebase = blockIdx.x * 1024;
  const int sh = P.shift[r];
  int dsts[4]; unsigned pk[4]; int bks[4];
#pragma unroll
  for (int k = 0; k < 4; ++k) {
    int e = ebase + k * 256 + tid;
    int d = P.dst[r][e];
    dsts[k] = d;
    pk[k] = (unsigned)P.src[r][e] | ((unsigned)f2bf(P.w[r][e]) << 16);
    bks[k] = d >> sh;
    atomicAdd(&hist[bks[k]], 1);
  }
  __syncthreads();
  if (tid < 64) {
    int c = hist[tid];
    if (c) lbase[tid] = atomicAdd(&ccur[r * 64 + tid], c);
  }
  __syncthreads();
#pragma unroll
  for (int k = 0; k < 4; ++k) {
    int pos = lbase[bks[k]] + atomicAdd(&lcur[bks[k]], 1);
    tmp[(size_t)r * NE + pos] = make_int2(dsts[k], (int)pk[k]);
  }
}

// ---- shared GEMM pieces: 64 rows x (256x256) bf16 MFMA (rounds 6-18 proven) ----
__device__ __forceinline__ void stage_x_f32(const float* __restrict__ g, int r0,
                                            unsigned short* xs, int tid) {
#pragma unroll
  for (int it = 0; it < 16; ++it) {
    int i = it * 256 + tid;
    int row = i >> 6, q = i & 63;
    float4 v = reinterpret_cast<const float4*>(g)[(size_t)(r0 + row) * 64 + q];
    ushort4 b;
    b.x = f2bf(v.x); b.y = f2bf(v.y); b.z = f2bf(v.z); b.w = f2bf(v.w);
    *reinterpret_cast<ushort4*>(&xs[row * 264 + q * 4]) = b;
  }
}

__device__ __forceinline__ void gemm_frag(const unsigned short* xs,
                                          const unsigned short* __restrict__ Wg,
                                          unsigned short* wl, int tid,
                                          f32x4 accv[4][4]) {
  const int wid = tid >> 6, lhi = (tid & 63) >> 4, llo = tid & 15;
  for (int ks = 0; ks < 8; ++ks) {
    const int k0 = ks * 32;
    __syncthreads();  // protects xs (first iter) and wl reads from prev iter
    {
      const uint4* gp = reinterpret_cast<const uint4*>(Wg + (size_t)tid * 256 + k0);
      uint4 a0 = gp[0], a1 = gp[1], a2 = gp[2], a3 = gp[3];
      uint4* lp = reinterpret_cast<uint4*>(wl + tid * 56);
      lp[0] = a0; lp[1] = a1; lp[2] = a2; lp[3] = a3;
    }
    __syncthreads();
    bf16x8 afr[4], bfr[4];
#pragma unroll
    for (int rt = 0; rt < 4; ++rt)
      afr[rt] = *reinterpret_cast<const bf16x8*>(&xs[(rt * 16 + llo) * 264 + k0 + lhi * 8]);
#pragma unroll
    for (int nt = 0; nt < 4; ++nt)
      bfr[nt] = *reinterpret_cast<const bf16x8*>(&wl[(wid * 64 + nt * 16 + llo) * 56 + lhi * 8]);
#pragma unroll
    for (int rt = 0; rt < 4; ++rt)
#pragma unroll
      for (int nt = 0; nt < 4; ++nt)
        accv[rt][nt] = __builtin_amdgcn_mfma_f32_16x16x32_bf16(afr[rt], bfr[nt], accv[rt][nt], 0, 0, 0);
  }
}

// ---- writeout: accv -> fp8 e4m3 bytes (hp row = 256 B) ----
__device__ __forceinline__ void writeout_hp(unsigned char* __restrict__ hp, int r0, int tid,
                                            f32x4 accv[4][4]) {
  const int wid = tid >> 6, lane = tid & 63, lhi = lane >> 4, llo = lane & 15;
#pragma unroll
  for (int rt = 0; rt < 4; ++rt)
#pragma unroll
    for (int nt = 0; nt < 4; ++nt) {
      int col = wid * 64 + nt * 16 + llo;
#pragma unroll
      for (int rg = 0; rg < 4; ++rg) {
        int row = rt * 16 + lhi * 4 + rg;
        int pk = __builtin_amdgcn_cvt_pk_fp8_f32(accv[rt][nt][rg], accv[rt][nt][rg], 0, false);
        hp[(size_t)(r0 + row) * DIM + col] = (unsigned char)(pk & 0xff);
      }
    }
}

// ---- mid kernel: partB (blocks [0,384)) ∥ transformT (blocks [384,1280)) ----
// partB emits PADDED buckets (pend-pstart = ceil(cnt/8)*8, pads zero-filled).
__global__ __launch_bounds__(256) void mid_kernel(const int2* __restrict__ tmp,
                                                  const int* __restrict__ cbase,
                                                  const int* __restrict__ pbase,
                                                  int* __restrict__ poffs,
                                                  int* __restrict__ pends,
                                                  unsigned* __restrict__ srcw,
                                                  NTab N, TTy T) {
  __shared__ union alignas(16) SM {
    struct { unsigned short xs[64 * 264]; unsigned short wl[256 * 56]; } t;
    struct { int hist[512]; int part[256]; int pend[512]; } p;
  } sm;
  const int bid = blockIdx.x, tid = threadIdx.x;

  if (bid < 384) {
    // ---------------- partB path (padded placement) ----------------
    int r = bid >> 6, b = bid & 63;
    const int n = N.n[r], s = n >> 6;
    const int dbase = b * s;
    int* hist = sm.p.hist;
    int* part = sm.p.part;
    int* pendL = sm.p.pend;
    for (int i = tid; i < s; i += 256) hist[i] = 0;
    __syncthreads();
    const int wbeg = cbase[r * 65 + b], wend = cbase[r * 65 + b + 1];
    const int2* __restrict__ tr = tmp + (size_t)r * NE;
    for (int i = wbeg + tid; i < wend; i += 256)
      atomicAdd(&hist[tr[i].x - dbase], 1);
    __syncthreads();
    const int per = (s > 256) ? 2 : 1;
    const int base = tid * per;
    int pv[2];
    int mysum = 0;
#pragma unroll
    for (int j = 0; j < 2; ++j) {
      int idx = base + j;
      int cnt = (j < per && idx < s) ? hist[idx] : 0;
      pv[j] = (cnt + 7) & ~7;          // padded bucket length
      mysum += pv[j];
    }
    part[tid] = mysum;
    __syncthreads();
    for (int off = 1; off < 256; off <<= 1) {
      int v = (tid >= off) ? part[tid - off] : 0;
      __syncthreads();
      part[tid] += v;
      __syncthreads();
    }
    int run = part[tid] - mysum + pbase[r * 65 + b];
#pragma unroll
    for (int j = 0; j < 2; ++j) {
      int idx = base + j;
      if (j < per && idx < s) {
        hist[idx] = run;                               // live cursor (real entries)
        pendL[idx] = run + pv[j];
        poffs[r * HSTRIDE + dbase + idx] = run;        // padded start
        pends[r * HSTRIDE + dbase + idx] = run + pv[j];// padded end
        run += pv[j];
      }
    }
    __syncthreads();
    unsigned* __restrict__ swr = srcw + (size_t)r * PADNE;
    for (int i = wbeg + tid; i < wend; i += 256) {
      int2 e = tr[i];
      int pos = atomicAdd(&hist[e.x - dbase], 1);
      swr[pos] = (unsigned)e.y;
    }
    __syncthreads();
    // zero-fill pad slots (src=0, w=+0.0 -> exact no-op in gather)
    for (int i = tid; i < s; i += 256)
      for (int p = hist[i]; p < pendL[i]; ++p) swr[p] = 0u;
  } else {
    // ---------------- transformT path (fp8 writeout) ----------------
    const int bx = bid - 384;
    int t = 0;
#pragma unroll
    for (int k = 1; k < 3; ++k) t += (bx >= T.cum[k]);
    const int r0 = (bx - T.cum[t]) * 64;

    stage_x_f32(T.h[t], r0, sm.t.xs, tid);

    f32x4 accv[4][4];
#pragma unroll
    for (int a = 0; a < 4; ++a)
#pragma unroll
      for (int b2 = 0; b2 < 4; ++b2) accv[a][b2] = {0.f, 0.f, 0.f, 0.f};
    gemm_frag(sm.t.xs, T.wA[t], sm.t.wl, tid, accv);
    writeout_hp(T.hpA[t], r0, tid, accv);

#pragma unroll
    for (int a = 0; a < 4; ++a)
#pragma unroll
      for (int b2 = 0; b2 < 4; ++b2) accv[a][b2] = {0.f, 0.f, 0.f, 0.f};
    gemm_frag(sm.t.xs, T.wB[t], sm.t.wl, tid, accv);  // first barrier inside protects wl reuse
    writeout_hp(T.hpB[t], r0, tid, accv);
  }
}

// ---- bucket walk (fp8 rows, packed f32 math, guard-free: buckets are 8-padded) ----
__device__ __forceinline__ void bucket_msg(const unsigned* __restrict__ sw,
                                           const unsigned char* __restrict__ hp,
                                           int beg, int end, int half, int c8,
                                           float& m0, float& m1, float& m2, float& m3,
                                           float& m4, float& m5, float& m6, float& m7) {
  f32x2 a01 = {0.f, 0.f}, a23 = {0.f, 0.f}, a45 = {0.f, 0.f}, a67 = {0.f, 0.f};
  float degw = 0.f;
  const int boff = c8 * 8;
  for (int j = beg; j < end; j += 8) {
    int ib = j + half * 4;
    unsigned e0 = sw[ib + 0], e1 = sw[ib + 1], e2 = sw[ib + 2], e3 = sw[ib + 3];
    float w0 = bfhi(e0), w1 = bfhi(e1), w2 = bfhi(e2), w3 = bfhi(e3);
    uint2 x0 = *reinterpret_cast<const uint2*>(hp + (size_t)(e0 & 0xffff) * DIM + boff);
    uint2 x1 = *reinterpret_cast<const uint2*>(hp + (size_t)(e1 & 0xffff) * DIM + boff);
    uint2 x2 = *reinterpret_cast<const uint2*>(hp + (size_t)(e2 & 0xffff) * DIM + boff);
    uint2 x3 = *reinterpret_cast<const uint2*>(hp + (size_t)(e3 & 0xffff) * DIM + boff);
    degw += (w0 + w1) + (w2 + w3);
    f32x2 wv0 = {w0, w0}, wv1 = {w1, w1}, wv2 = {w2, w2}, wv3 = {w3, w3};
    a01 += wv0 * __builtin_amdgcn_cvt_pk_f32_fp8(x0.x, false);
    a23 += wv0 * __builtin_amdgcn_cvt_pk_f32_fp8(x0.x, true);
    a45 += wv0 * __builtin_amdgcn_cvt_pk_f32_fp8(x0.y, false);
    a67 += wv0 * __builtin_amdgcn_cvt_pk_f32_fp8(x0.y, true);
    a01 += wv1 * __builtin_amdgcn_cvt_pk_f32_fp8(x1.x, false);
    a23 += wv1 * __builtin_amdgcn_cvt_pk_f32_fp8(x1.x, true);
    a45 += wv1 * __builtin_amdgcn_cvt_pk_f32_fp8(x1.y, false);
    a67 += wv1 * __builtin_amdgcn_cvt_pk_f32_fp8(x1.y, true);
    a01 += wv2 * __builtin_amdgcn_cvt_pk_f32_fp8(x2.x, false);
    a23 += wv2 * __builtin_amdgcn_cvt_pk_f32_fp8(x2.x, true);
    a45 += wv2 * __builtin_amdgcn_cvt_pk_f32_fp8(x2.y, false);
    a67 += wv2 * __builtin_amdgcn_cvt_pk_f32_fp8(x2.y, true);
    a01 += wv3 * __builtin_amdgcn_cvt_pk_f32_fp8(x3.x, false);
    a23 += wv3 * __builtin_amdgcn_cvt_pk_f32_fp8(x3.x, true);
    a45 += wv3 * __builtin_amdgcn_cvt_pk_f32_fp8(x3.y, false);
    a67 += wv3 * __builtin_amdgcn_cvt_pk_f32_fp8(x3.y, true);
  }
  float a0 = a01.x, a1 = a01.y, a2 = a23.x, a3 = a23.y;
  float a4 = a45.x, a5 = a45.y, a6 = a67.x, a7 = a67.y;
  a0 += __shfl_xor(a0, 32); a1 += __shfl_xor(a1, 32);
  a2 += __shfl_xor(a2, 32); a3 += __shfl_xor(a3, 32);
  a4 += __shfl_xor(a4, 32); a5 += __shfl_xor(a5, 32);
  a6 += __shfl_xor(a6, 32); a7 += __shfl_xor(a7, 32);
  degw += __shfl_xor(degw, 32);
  float inv = (degw == 0.f) ? 1.f : 1.f / degw;
  m0 = a0 * inv; m1 = a1 * inv; m2 = a2 * inv; m3 = a3 * inv;
  m4 = a4 * inv; m5 = a5 * inv; m6 = a6 * inv; m7 = a7 * inv;
}

// ---- gather + relation attention: agg[node] = c1*mA + (1-c1)*mB (bf16) ----
// softmax over 2 relations == sigmoid of score difference: c1 = ¼ Σ_h σ(0.125·(sA_h−sB_h))
__global__ __launch_bounds__(256) void gatherAtt_kernel(GATab T) {
  const int bx = blockIdx.x;
  int t = 0;
#pragma unroll
  for (int k = 1; k < 3; ++k) t += (bx >= T.cum[k]);
  const int node = (bx - T.cum[t]) * 4 + (threadIdx.x >> 6);
  const int lane = threadIdx.x & 63;
  const int half = lane >> 5;
  const int c8 = lane & 31;

  float mA0, mA1, mA2, mA3, mA4, mA5, mA6, mA7;
  float mB0, mB1, mB2, mB3, mB4, mB5, mB6, mB7;
  bucket_msg(T.swA[t], T.hpA[t], T.poA[t][node], T.peA[t][node], half, c8,
             mA0, mA1, mA2, mA3, mA4, mA5, mA6, mA7);
  bucket_msg(T.swB[t], T.hpB[t], T.poB[t][node], T.peB[t][node], half, c8,
             mB0, mB1, mB2, mB3, mB4, mB5, mB6, mB7);

  // difference dots, packed by head pair: dp0={d_h0,d_h1}, dp1={d_h2,d_h3}
  const f32x2* __restrict__ A1p = T.A1p[t];  // [2][256] head-pair packed
  const f32x2* __restrict__ A2p = T.A2p[t];
  const int db = c8 * 8;
  f32x2 dp0 = {0.f, 0.f}, dp1 = {0.f, 0.f};
  {
    f32x2 w;
#define DOTSTEP(J, MA, MB)                                      \
    w = (f32x2){MA, MA};                                        \
    dp0 += w * A1p[db + J]; dp1 += w * A1p[256 + db + J];       \
    w = (f32x2){MB, MB};                                        \
    dp0 -= w * A2p[db + J]; dp1 -= w * A2p[256 + db + J];
    DOTSTEP(0, mA0, mB0) DOTSTEP(1, mA1, mB1)
    DOTSTEP(2, mA2, mB2) DOTSTEP(3, mA3, mB3)
    DOTSTEP(4, mA4, mB4) DOTSTEP(5, mA5, mB5)
    DOTSTEP(6, mA6, mB6) DOTSTEP(7, mA7, mB7)
#undef DOTSTEP
  }
#pragma unroll
  for (int o = 1; o <= 16; o <<= 1) {
    dp0 += __builtin_bit_cast(f32x2, __shfl_xor(__builtin_bit_cast(double, dp0), o));
    dp1 += __builtin_bit_cast(f32x2, __shfl_xor(__builtin_bit_cast(double, dp1), o));
  }
  // c1 = mean over heads of sigmoid(0.125 * d_h); c2 = 1 - c1 (exact)
  float c1 = 1.f / (1.f + __expf(-0.125f * dp0.x))
           + 1.f / (1.f + __expf(-0.125f * dp0.y))
           + 1.f / (1.f + __expf(-0.125f * dp1.x))
           + 1.f / (1.f + __expf(-0.125f * dp1.y));
  c1 *= 0.25f;
  float c2 = 1.f - c1;

  if (half == 0) {
    u32x4 o;
    o.x = (unsigned)f2bf(c1 * mA0 + c2 * mB0) | ((unsigned)f2bf(c1 * mA1 + c2 * mB1) << 16);
    o.y = (unsigned)f2bf(c1 * mA2 + c2 * mB2) | ((unsigned)f2bf(c1 * mA3 + c2 * mB3) << 16);
    o.z = (unsigned)f2bf(c1 * mA4 + c2 * mB4) | ((unsigned)f2bf(c1 * mA5 + c2 * mB5) << 16);
    o.w = (unsigned)f2bf(c1 * mA6 + c2 * mB6) | ((unsigned)f2bf(c1 * mA7 + c2 * mB7) << 16);
    __builtin_nontemporal_store(o, reinterpret_cast<u32x4*>(T.agg[t]) + (size_t)node * 32 + c8);
  }
}

// ---- all 3 types merged: self-GEMM + agg + residual + LN + leaky (rounds 15-18 proven) ----
__global__ __launch_bounds__(256) void fuse3_kernel(FTab F) {
  __shared__ alignas(16) union SM {
    struct { unsigned short x[64 * 264]; unsigned short w[256 * 56]; } g;
    unsigned short s[64 * 260];  // self result, bf16
  } ov;
  __shared__ float sgb[512];
  const int tid = threadIdx.x;
  const int bx = blockIdx.x;
  int t = 0;
#pragma unroll
  for (int k = 1; k < 3; ++k) t += (bx >= F.cum[k]);
  const int r0 = (bx - F.cum[t]) * 64;
  const float* __restrict__ h = F.h[t];
  const unsigned short* __restrict__ agg = F.agg[t];

  stage_x_f32(h, r0, ov.g.x, tid);
  for (int i = tid; i < 512; i += 256) sgb[i] = (i < 256) ? F.gm[t][i] : F.bt[t][i - 256];

  f32x4 accv[4][4];
#pragma unroll
  for (int a = 0; a < 4; ++a)
#pragma unroll
    for (int b = 0; b < 4; ++b) accv[a][b] = {0.f, 0.f, 0.f, 0.f};

  gemm_frag(ov.g.x, F.wbf[t], ov.g.w, tid, accv);

  const int wid = tid >> 6, lane = tid & 63, lhi = lane >> 4, llo = lane & 15;
  __syncthreads();  // all MFMA LDS reads done before overlaying ov.s
#pragma unroll
  for (int rt = 0; rt < 4; ++rt)
#pragma unroll
    for (int nt = 0; nt < 4; ++nt) {
      int col = wid * 64 + nt * 16 + llo;
#pragma unroll
      for (int rg = 0; rg < 4; ++rg)
        ov.s[(rt * 16 + lhi * 4 + rg) * 260 + col] = f2bf(accv[rt][nt][rg]);
    }
  __syncthreads();

  // epilogue: wave handles 16 rows; lane owns 4 dims
  const int d0 = lane * 4;
  const float4 g4 = *reinterpret_cast<const float4*>(&sgb[d0]);
  const float4 b4 = *reinterpret_cast<const float4*>(&sgb[256 + d0]);
  float* __restrict__ outp = F.out[t];

  for (int rl = 0; rl < 16; ++rl) {
    int row = wid * 16 + rl;
    size_t gb = (size_t)(r0 + row) * DIM + d0;
    ushort4 ab = *reinterpret_cast<const ushort4*>(agg + gb);
    float4 av = {bf2f(ab.x), bf2f(ab.y), bf2f(ab.z), bf2f(ab.w)};
    float4 hvv = *reinterpret_cast<const float4*>(h + gb);
    ushort4 sb = *reinterpret_cast<const ushort4*>(&ov.s[row * 260 + d0]);
    float4 sv = {bf2f(sb.x), bf2f(sb.y), bf2f(sb.z), bf2f(sb.w)};

    float4 u;
    u.x = sv.x + av.x + hvv.x;
    u.y = sv.y + av.y + hvv.y;
    u.z = sv.z + av.z + hvv.z;
    u.w = sv.w + av.w + hvv.w;

    float s1v = u.x + u.y + u.z + u.w;
    float s2v = u.x * u.x + u.y * u.y + u.z * u.z + u.w * u.w;
#pragma unroll
    for (int o = 1; o < 64; o <<= 1) { s1v += __shfl_xor(s1v, o); s2v += __shfl_xor(s2v, o); }
    float mu = s1v * (1.f / 256.f);
    float var = s2v * (1.f / 256.f) - mu * mu;
    float rstd = rsqrtf(var + 1e-5f);

    float4 y;
    y.x = (u.x - mu) * rstd * g4.x + b4.x;
    y.y = (u.y - mu) * rstd * g4.y + b4.y;
    y.z = (u.z - mu) * rstd * g4.z + b4.z;
    y.w = (u.w - mu) * rstd * g4.w + b4.w;
    y.x = fmaxf(y.x, 0.01f * y.x);
    y.y = fmaxf(y.y, 0.01f * y.y);
    y.z = fmaxf(y.z, 0.01f * y.z);
    y.w = fmaxf(y.w, 0.01f * y.w);
    *reinterpret_cast<float4*>(outp + gb) = y;
  }
}

// ---- workspace layout (bytes); ~88 MB (< proven ~139 MB) ----
static constexpr size_t AL(size_t x) { return (x + 255) & ~size_t(255); }
// aggregated messages (bf16), one row per node, type-major l|g|d
static constexpr size_t AGG_TOT = (size_t)(NLr + NGr + NDr) * DIM;      // ushorts
// transformed embeddings (fp8, 1 byte/elem), all 6 relations, sized by SRC rows
static constexpr size_t HPe_L2G = 0;                                    // NLr rows
static constexpr size_t HPe_G2L = HPe_L2G + (size_t)NLr * DIM;          // NGr
static constexpr size_t HPe_G2D = HPe_G2L + (size_t)NGr * DIM;          // NGr
static constexpr size_t HPe_D2G = HPe_G2D + (size_t)NGr * DIM;          // NDr
static constexpr size_t HPe_L2D = HPe_D2G + (size_t)NDr * DIM;          // NLr
static constexpr size_t HPe_D2L = HPe_L2D + (size_t)NLr * DIM;          // NDr
static constexpr size_t HP_TOT  = HPe_D2L + (size_t)NDr * DIM;          // bytes
static constexpr size_t OFF_AGG   = 0;
static constexpr size_t OFF_HP    = AL(OFF_AGG + AGG_TOT * 2);
static constexpr size_t OFF_WBF   = AL(OFF_HP + HP_TOT);
static constexpr size_t OFF_POFF  = AL(OFF_WBF + 9 * 65536 * 2);        // 6*HSTRIDE ints
static constexpr size_t OFF_PEND  = AL(OFF_POFF + 6 * HSTRIDE * 4);     // 6*HSTRIDE ints
static constexpr size_t OFF_CHIST = AL(OFF_PEND + 6 * HSTRIDE * 4);     // 384 ints
static constexpr size_t OFF_CBASE = AL(OFF_CHIST + 384 * 4);            // 6*65 ints
static constexpr size_t OFF_PBASE = AL(OFF_CBASE + 390 * 4);            // 6*65 ints
static constexpr size_t OFF_CCUR  = AL(OFF_PBASE + 390 * 4);            // 384 ints
static constexpr size_t OFF_APK   = AL(OFF_CCUR + 384 * 4);             // 6*512 f32x2
static constexpr size_t OFF_TMP   = AL(OFF_APK + 6 * 512 * 8);          // 6*NE int2
static constexpr size_t OFF_SRCW  = AL(OFF_TMP + (size_t)6 * NE * 8);   // 6*PADNE u32

extern "C" void kernel_launch(void* const* d_in, const int* in_sizes, int n_in,
                              void* d_out, int out_size, void* d_ws, size_t ws_size,
                              hipStream_t stream) {
  char* wsb = (char*)d_ws;
  unsigned short* agg = (unsigned short*)(wsb + OFF_AGG);
  unsigned char* hp   = (unsigned char*)(wsb + OFF_HP);
  unsigned short* wbf = (unsigned short*)(wsb + OFF_WBF);
  int* poffs = (int*)(wsb + OFF_POFF);
  int* pends = (int*)(wsb + OFF_PEND);
  int* chist = (int*)(wsb + OFF_CHIST);
  int* cbase = (int*)(wsb + OFF_CBASE);
  int* pbase = (int*)(wsb + OFF_PBASE);
  int* ccur  = (int*)(wsb + OFF_CCUR);
  f32x2* apk = (f32x2*)(wsb + OFF_APK);
  int2* tmp  = (int2*)(wsb + OFF_TMP);
  unsigned* srcw = (unsigned*)(wsb + OFF_SRCW);
  float* out = (float*)d_out;

  // relation order: l2g, g2l, g2d, d2g, l2d, d2l
  const int base[6] = {3, 8, 13, 18, 23, 28};
  const int ndst[6] = {NGr, NLr, NDr, NGr, NDr, NLr};
  const size_t hpOff[6]  = {HPe_L2G, HPe_G2L, HPe_G2D, HPe_D2G, HPe_L2D, HPe_D2L};

  // merged prep: weight f32->bf16 + coarse dst histogram + A-matrix head-pair pack
  (void)hipMemsetAsync(chist, 0, 384 * 4, stream);
  PrepTab Q; PTab P; NTab N;
  Q.wsrc[0] = (const float*)d_in[6];  Q.wsrc[1] = (const float*)d_in[11];
  Q.wsrc[2] = (const float*)d_in[16]; Q.wsrc[3] = (const float*)d_in[21];
  Q.wsrc[4] = (const float*)d_in[26]; Q.wsrc[5] = (const float*)d_in[31];
  Q.wsrc[6] = (const float*)d_in[33]; Q.wsrc[7] = (const float*)d_in[36];
  Q.wsrc[8] = (const float*)d_in[39];
  // A-pack order: [A1_l, A2_l, A1_g, A2_g, A1_d, A2_d]
  Q.apack[0] = (const float*)d_in[12]; Q.apack[1] = (const float*)d_in[32];
  Q.apack[2] = (const float*)d_in[7];  Q.apack[3] = (const float*)d_in[22];
  Q.apack[4] = (const float*)d_in[17]; Q.apack[5] = (const float*)d_in[27];
  for (int r = 0; r < 6; ++r) {
    int sh = (ndst[r] == NGr) ? 9 : (ndst[r] == NLr ? 8 : 7);  // coarse = n>>6
    Q.dst[r] = (const int*)d_in[base[r] + 1];
    Q.shift[r] = sh;
    P.src[r] = (const int*)d_in[base[r]];
    P.dst[r] = (const int*)d_in[base[r] + 1];
    P.w[r]  = (const float*)d_in[base[r] + 2];
    P.shift[r] = sh;
    N.n[r] = ndst[r];
  }
  prep_kernel<<<2304 + 1536 + 6, 256, 0, stream>>>(Q, wbf, chist, apk);
  scan384_kernel<<<1, 64, 0, stream>>>(chist, ccur, cbase, pbase, N);

  // partition pass A (coarse)
  partA6_kernel<<<dim3(NE / 1024, 6), 256, 0, stream>>>(P, ccur, tmp);

  // mid: partB (padded fine placement + poffs/pends) OVERLAPPED with transformT
  // type l -> {l2g(0), l2d(4)}, type g -> {g2l(1), g2d(2)}, type d -> {d2g(3), d2l(5)}
  TTy T;
  T.h[0] = (const float*)d_in[0]; T.h[1] = (const float*)d_in[1]; T.h[2] = (const float*)d_in[2];
  T.hpA[0] = hp + hpOff[0]; T.hpB[0] = hp + hpOff[4];
  T.hpA[1] = hp + hpOff[1]; T.hpB[1] = hp + hpOff[2];
  T.hpA[2] = hp + hpOff[3]; T.hpB[2] = hp + hpOff[5];
  T.wA[0] = wbf + 0 * 65536; T.wB[0] = wbf + 4 * 65536;
  T.wA[1] = wbf + 1 * 65536; T.wB[1] = wbf + 2 * 65536;
  T.wA[2] = wbf + 3 * 65536; T.wB[2] = wbf + 5 * 65536;
  T.cum[0] = 0; T.cum[1] = NLr / 64; T.cum[2] = (NLr + NGr) / 64; T.cum[3] = (NLr + NGr + NDr) / 64;
  mid_kernel<<<384 + 896, 256, 0, stream>>>(tmp, cbase, pbase, poffs, pends, srcw, N, T);

  // gather + attention per dest type: l <- {g2l(1), d2l(5)}, g <- {l2g(0), d2g(3)},
  // d <- {g2d(2), l2d(4)}; one wave per node, serial two-bucket walk (padded fp8 rows)
  GATab G;
  const int relA[3] = {1, 0, 2}, relB[3] = {5, 3, 4};
  const size_t aggBase[3] = {0, (size_t)NLr * DIM, (size_t)(NLr + NGr) * DIM};
  for (int t = 0; t < 3; ++t) {
    G.hpA[t] = hp + hpOff[relA[t]];
    G.hpB[t] = hp + hpOff[relB[t]];
    G.swA[t] = srcw + (size_t)relA[t] * PADNE;
    G.swB[t] = srcw + (size_t)relB[t] * PADNE;
    G.poA[t] = poffs + relA[t] * HSTRIDE;
    G.peA[t] = pends + relA[t] * HSTRIDE;
    G.poB[t] = poffs + relB[t] * HSTRIDE;
    G.peB[t] = pends + relB[t] * HSTRIDE;
    G.A1p[t] = apk + (size_t)(t * 2) * 512;
    G.A2p[t] = apk + (size_t)(t * 2 + 1) * 512;
    G.agg[t] = agg + aggBase[t];
  }
  G.cum[0] = 0; G.cum[1] = NLr / 4; G.cum[2] = (NLr + NGr) / 4; G.cum[3] = (NLr + NGr + NDr) / 4;
  gatherAtt_kernel<<<G.cum[3], 256, 0, stream>>>(G);

  // fused update, all 3 types in one launch
  FTab F;
  F.h[0] = (const float*)d_in[0]; F.h[1] = (const float*)d_in[1]; F.h[2] = (const float*)d_in[2];
  F.agg[0] = agg + aggBase[0]; F.agg[1] = agg + aggBase[1]; F.agg[2] = agg + aggBase[2];
  F.wbf[0] = wbf + 6 * 65536; F.wbf[1] = wbf + 7 * 65536; F.wbf[2] = wbf + 8 * 65536;
  F.gm[0] = (const float*)d_in[34]; F.bt[0] = (const float*)d_in[35];
  F.gm[1] = (const float*)d_in[37]; F.bt[1] = (const float*)d_in[38];
  F.gm[2] = (const float*)d_in[40]; F.bt[2] = (const float*)d_in[41];
  F.out[0] = out;
  F.out[1] = out + (size_t)NLr * DIM;
  F.out[2] = out + (size_t)(NLr + NGr) * DIM;
  F.cum[0] = 0; F.cum[1] = NLr / 64; F.cum[2] = (NLr + NGr) / 64; F.cum[3] = (NLr + NGr + NDr) / 64;
  fuse3_kernel<<<F.cum[3], 256, 0, stream>>>(F);
}

// Round 20
// 233.991 us; speedup vs baseline: 1.1585x; 1.1585x over previous
//
#include <hip/hip_runtime.h>

#define DIM 256
#define NLr 16384
#define NGr 32768
#define NDr 8192
#define NE  262144
#define PADNE 524288   // padded srcw stride: NE + 8*max_n
#define HSTRIDE 32772  // poffs/pends per-relation stride (16B-aligned)

typedef short bf16x8 __attribute__((ext_vector_type(8)));
typedef float f32x4 __attribute__((ext_vector_type(4)));
typedef float f32x2 __attribute__((ext_vector_type(2)));
typedef unsigned u32x4 __attribute__((ext_vector_type(4)));

__device__ __forceinline__ unsigned short f2bf(float f) {
  unsigned int u = __builtin_bit_cast(unsigned int, f);
  u += 0x7fffu + ((u >> 16) & 1u);
  return (unsigned short)(u >> 16);
}
__device__ __forceinline__ float bf2f(unsigned short b) {
  return __builtin_bit_cast(float, ((unsigned int)b) << 16);
}
__device__ __forceinline__ float bfhi(unsigned int u) {
  return __builtin_bit_cast(float, u & 0xffff0000u);
}

struct NTab { int n[6]; };
struct PrepTab { const float* wsrc[9]; const int* dst[6]; int shift[6]; };
struct PTab { const int* src[6]; const int* dst[6]; const float* w[6]; int shift[6]; };
struct TTy { const float* h[3]; unsigned char* hpA[3]; unsigned char* hpB[3];
             const unsigned short* wA[3]; const unsigned short* wB[3]; int cum[4]; };
struct GATab { const unsigned char* hpA[3]; const unsigned char* hpB[3];
               const unsigned* swA[3]; const unsigned* swB[3];
               const int* poA[3]; const int* peA[3];
               const int* poB[3]; const int* peB[3];
               const float* A1[3]; const float* A2[3];
               unsigned short* agg[3]; int cum[4]; };
struct FTab { const float* h[3]; const unsigned short* agg[3];
              const unsigned short* wbf[3]; const float* gm[3]; const float* bt[3];
              float* out[3]; int cum[4]; };

// ---- merged prep: blocks [0,2304) convert 9 weight mats; [2304,3840) coarse hist ----
__global__ __launch_bounds__(256) void prep_kernel(PrepTab Q, unsigned short* __restrict__ wbf,
                                                   int* __restrict__ chist) {
  const int bid = blockIdx.x, tid = threadIdx.x;
  __shared__ int h[64];
  if (bid < 2304) {
    int m = bid >> 8;
    int i = (bid & 255) * 256 + tid;
    wbf[m * 65536 + i] = f2bf(Q.wsrc[m][i]);
  } else {
    int b2 = bid - 2304;
    int r = b2 >> 8;          // 256 blocks per relation, 1024 edges each
    int blk = b2 & 255;
    if (tid < 64) h[tid] = 0;
    __syncthreads();
    const int* dp = Q.dst[r] + blk * 1024;
    const int sh = Q.shift[r];
#pragma unroll
    for (int k = 0; k < 4; ++k) atomicAdd(&h[dp[k * 256 + tid] >> sh], 1);
    __syncthreads();
    if (tid < 64) { int c = h[tid]; if (c) atomicAdd(&chist[r * 64 + tid], c); }
  }
}

// ---- tiny coarse scan: ccur (partA cursor), cbase (tmp windows), pbase (padded srcw) ----
__global__ void scan384_kernel(const int* __restrict__ chist, int* __restrict__ ccur,
                               int* __restrict__ cbase, int* __restrict__ pbase, NTab N) {
  int r = threadIdx.x;
  if (r < 6) {
    int off = 0, offp = 0;
    int s8 = (N.n[r] >> 6) * 8;   // per-window pad slack
    for (int b = 0; b < 64; ++b) {
      ccur[r * 64 + b] = off;
      cbase[r * 65 + b] = off;
      pbase[r * 65 + b] = offp;
      off += chist[r * 64 + b];
      offp += chist[r * 64 + b] + s8;
    }
    cbase[r * 65 + 64] = off;  // == NE
  }
}

// ---- partition pass A: coarse 64-bucket partition into tmp (dst, packed) ----
__global__ __launch_bounds__(256) void partA6_kernel(PTab P, int* __restrict__ ccur,
                                                     int2* __restrict__ tmp) {
  int r = blockIdx.y;
  const int tid = threadIdx.x;
  __shared__ int hist[64], lbase[64], lcur[64];
  if (tid < 64) { hist[tid] = 0; lcur[tid] = 0; }
  __syncthreads();
  const int ebase = blockIdx.x * 1024;
  const int sh = P.shift[r];
  int dsts[4]; unsigned pk[4]; int bks[4];
#pragma unroll
  for (int k = 0; k < 4; ++k) {
    int e = ebase + k * 256 + tid;
    int d = P.dst[r][e];
    dsts[k] = d;
    pk[k] = (unsigned)P.src[r][e] | ((unsigned)f2bf(P.w[r][e]) << 16);
    bks[k] = d >> sh;
    atomicAdd(&hist[bks[k]], 1);
  }
  __syncthreads();
  if (tid < 64) {
    int c = hist[tid];
    if (c) lbase[tid] = atomicAdd(&ccur[r * 64 + tid], c);
  }
  __syncthreads();
#pragma unroll
  for (int k = 0; k < 4; ++k) {
    int pos = lbase[bks[k]] + atomicAdd(&lcur[bks[k]], 1);
    tmp[(size_t)r * NE + pos] = make_int2(dsts[k], (int)pk[k]);
  }
}

// ---- shared GEMM pieces: 64 rows x (256x256) bf16 MFMA (rounds 6-18 proven) ----
__device__ __forceinline__ void stage_x_f32(const float* __restrict__ g, int r0,
                                            unsigned short* xs, int tid) {
#pragma unroll
  for (int it = 0; it < 16; ++it) {
    int i = it * 256 + tid;
    int row = i >> 6, q = i & 63;
    float4 v = reinterpret_cast<const float4*>(g)[(size_t)(r0 + row) * 64 + q];
    ushort4 b;
    b.x = f2bf(v.x); b.y = f2bf(v.y); b.z = f2bf(v.z); b.w = f2bf(v.w);
    *reinterpret_cast<ushort4*>(&xs[row * 264 + q * 4]) = b;
  }
}

__device__ __forceinline__ void gemm_frag(const unsigned short* xs,
                                          const unsigned short* __restrict__ Wg,
                                          unsigned short* wl, int tid,
                                          f32x4 accv[4][4]) {
  const int wid = tid >> 6, lhi = (tid & 63) >> 4, llo = tid & 15;
  for (int ks = 0; ks < 8; ++ks) {
    const int k0 = ks * 32;
    __syncthreads();  // protects xs (first iter) and wl reads from prev iter
    {
      const uint4* gp = reinterpret_cast<const uint4*>(Wg + (size_t)tid * 256 + k0);
      uint4 a0 = gp[0], a1 = gp[1], a2 = gp[2], a3 = gp[3];
      uint4* lp = reinterpret_cast<uint4*>(wl + tid * 56);
      lp[0] = a0; lp[1] = a1; lp[2] = a2; lp[3] = a3;
    }
    __syncthreads();
    bf16x8 afr[4], bfr[4];
#pragma unroll
    for (int rt = 0; rt < 4; ++rt)
      afr[rt] = *reinterpret_cast<const bf16x8*>(&xs[(rt * 16 + llo) * 264 + k0 + lhi * 8]);
#pragma unroll
    for (int nt = 0; nt < 4; ++nt)
      bfr[nt] = *reinterpret_cast<const bf16x8*>(&wl[(wid * 64 + nt * 16 + llo) * 56 + lhi * 8]);
#pragma unroll
    for (int rt = 0; rt < 4; ++rt)
#pragma unroll
      for (int nt = 0; nt < 4; ++nt)
        accv[rt][nt] = __builtin_amdgcn_mfma_f32_16x16x32_bf16(afr[rt], bfr[nt], accv[rt][nt], 0, 0, 0);
  }
}

// ---- writeout: accv -> fp8 e4m3 bytes (hp row = 256 B) ----
__device__ __forceinline__ void writeout_hp(unsigned char* __restrict__ hp, int r0, int tid,
                                            f32x4 accv[4][4]) {
  const int wid = tid >> 6, lane = tid & 63, lhi = lane >> 4, llo = lane & 15;
#pragma unroll
  for (int rt = 0; rt < 4; ++rt)
#pragma unroll
    for (int nt = 0; nt < 4; ++nt) {
      int col = wid * 64 + nt * 16 + llo;
#pragma unroll
      for (int rg = 0; rg < 4; ++rg) {
        int row = rt * 16 + lhi * 4 + rg;
        int pk = __builtin_amdgcn_cvt_pk_fp8_f32(accv[rt][nt][rg], accv[rt][nt][rg], 0, false);
        hp[(size_t)(r0 + row) * DIM + col] = (unsigned char)(pk & 0xff);
      }
    }
}

// ---- mid kernel: partB (blocks [0,384)) ∥ transformT (blocks [384,1280)) ----
// partB emits PADDED buckets (pend-pstart = ceil(cnt/8)*8, pads zero-filled).
__global__ __launch_bounds__(256) void mid_kernel(const int2* __restrict__ tmp,
                                                  const int* __restrict__ cbase,
                                                  const int* __restrict__ pbase,
                                                  int* __restrict__ poffs,
                                                  int* __restrict__ pends,
                                                  unsigned* __restrict__ srcw,
                                                  NTab N, TTy T) {
  __shared__ union alignas(16) SM {
    struct { unsigned short xs[64 * 264]; unsigned short wl[256 * 56]; } t;
    struct { int hist[512]; int part[256]; int pend[512]; } p;
  } sm;
  const int bid = blockIdx.x, tid = threadIdx.x;

  if (bid < 384) {
    // ---------------- partB path (padded placement) ----------------
    int r = bid >> 6, b = bid & 63;
    const int n = N.n[r], s = n >> 6;
    const int dbase = b * s;
    int* hist = sm.p.hist;
    int* part = sm.p.part;
    int* pendL = sm.p.pend;
    for (int i = tid; i < s; i += 256) hist[i] = 0;
    __syncthreads();
    const int wbeg = cbase[r * 65 + b], wend = cbase[r * 65 + b + 1];
    const int2* __restrict__ tr = tmp + (size_t)r * NE;
    for (int i = wbeg + tid; i < wend; i += 256)
      atomicAdd(&hist[tr[i].x - dbase], 1);
    __syncthreads();
    const int per = (s > 256) ? 2 : 1;
    const int base = tid * per;
    int pv[2];
    int mysum = 0;
#pragma unroll
    for (int j = 0; j < 2; ++j) {
      int idx = base + j;
      int cnt = (j < per && idx < s) ? hist[idx] : 0;
      pv[j] = (cnt + 7) & ~7;          // padded bucket length
      mysum += pv[j];
    }
    part[tid] = mysum;
    __syncthreads();
    for (int off = 1; off < 256; off <<= 1) {
      int v = (tid >= off) ? part[tid - off] : 0;
      __syncthreads();
      part[tid] += v;
      __syncthreads();
    }
    int run = part[tid] - mysum + pbase[r * 65 + b];
#pragma unroll
    for (int j = 0; j < 2; ++j) {
      int idx = base + j;
      if (j < per && idx < s) {
        hist[idx] = run;                               // live cursor (real entries)
        pendL[idx] = run + pv[j];
        poffs[r * HSTRIDE + dbase + idx] = run;        // padded start
        pends[r * HSTRIDE + dbase + idx] = run + pv[j];// padded end
        run += pv[j];
      }
    }
    __syncthreads();
    unsigned* __restrict__ swr = srcw + (size_t)r * PADNE;
    for (int i = wbeg + tid; i < wend; i += 256) {
      int2 e = tr[i];
      int pos = atomicAdd(&hist[e.x - dbase], 1);
      swr[pos] = (unsigned)e.y;
    }
    __syncthreads();
    // zero-fill pad slots (src=0, w=+0.0 -> exact no-op in gather)
    for (int i = tid; i < s; i += 256)
      for (int p = hist[i]; p < pendL[i]; ++p) swr[p] = 0u;
  } else {
    // ---------------- transformT path (fp8 writeout) ----------------
    const int bx = bid - 384;
    int t = 0;
#pragma unroll
    for (int k = 1; k < 3; ++k) t += (bx >= T.cum[k]);
    const int r0 = (bx - T.cum[t]) * 64;

    stage_x_f32(T.h[t], r0, sm.t.xs, tid);

    f32x4 accv[4][4];
#pragma unroll
    for (int a = 0; a < 4; ++a)
#pragma unroll
      for (int b2 = 0; b2 < 4; ++b2) accv[a][b2] = {0.f, 0.f, 0.f, 0.f};
    gemm_frag(sm.t.xs, T.wA[t], sm.t.wl, tid, accv);
    writeout_hp(T.hpA[t], r0, tid, accv);

#pragma unroll
    for (int a = 0; a < 4; ++a)
#pragma unroll
      for (int b2 = 0; b2 < 4; ++b2) accv[a][b2] = {0.f, 0.f, 0.f, 0.f};
    gemm_frag(sm.t.xs, T.wB[t], sm.t.wl, tid, accv);  // first barrier inside protects wl reuse
    writeout_hp(T.hpB[t], r0, tid, accv);
  }
}

// ---- bucket walk: fp8 rows, f32x2 math, guard-free (padded %8 -> %4), 32-lane group ----
__device__ __forceinline__ void bucket_msg(const unsigned* __restrict__ sw,
                                           const unsigned char* __restrict__ hp,
                                           int beg, int end, int c8,
                                           float& m0, float& m1, float& m2, float& m3,
                                           float& m4, float& m5, float& m6, float& m7) {
  f32x2 a01 = {0.f, 0.f}, a23 = {0.f, 0.f}, a45 = {0.f, 0.f}, a67 = {0.f, 0.f};
  float degw = 0.f;
  const int boff = c8 * 8;
  for (int j = beg; j < end; j += 4) {
    unsigned e0 = sw[j + 0], e1 = sw[j + 1], e2 = sw[j + 2], e3 = sw[j + 3];
    float w0 = bfhi(e0), w1 = bfhi(e1), w2 = bfhi(e2), w3 = bfhi(e3);
    uint2 x0 = *reinterpret_cast<const uint2*>(hp + (size_t)(e0 & 0xffff) * DIM + boff);
    uint2 x1 = *reinterpret_cast<const uint2*>(hp + (size_t)(e1 & 0xffff) * DIM + boff);
    uint2 x2 = *reinterpret_cast<const uint2*>(hp + (size_t)(e2 & 0xffff) * DIM + boff);
    uint2 x3 = *reinterpret_cast<const uint2*>(hp + (size_t)(e3 & 0xffff) * DIM + boff);
    degw += (w0 + w1) + (w2 + w3);
    f32x2 wv0 = {w0, w0}, wv1 = {w1, w1}, wv2 = {w2, w2}, wv3 = {w3, w3};
    a01 += wv0 * __builtin_amdgcn_cvt_pk_f32_fp8(x0.x, false);
    a23 += wv0 * __builtin_amdgcn_cvt_pk_f32_fp8(x0.x, true);
    a45 += wv0 * __builtin_amdgcn_cvt_pk_f32_fp8(x0.y, false);
    a67 += wv0 * __builtin_amdgcn_cvt_pk_f32_fp8(x0.y, true);
    a01 += wv1 * __builtin_amdgcn_cvt_pk_f32_fp8(x1.x, false);
    a23 += wv1 * __builtin_amdgcn_cvt_pk_f32_fp8(x1.x, true);
    a45 += wv1 * __builtin_amdgcn_cvt_pk_f32_fp8(x1.y, false);
    a67 += wv1 * __builtin_amdgcn_cvt_pk_f32_fp8(x1.y, true);
    a01 += wv2 * __builtin_amdgcn_cvt_pk_f32_fp8(x2.x, false);
    a23 += wv2 * __builtin_amdgcn_cvt_pk_f32_fp8(x2.x, true);
    a45 += wv2 * __builtin_amdgcn_cvt_pk_f32_fp8(x2.y, false);
    a67 += wv2 * __builtin_amdgcn_cvt_pk_f32_fp8(x2.y, true);
    a01 += wv3 * __builtin_amdgcn_cvt_pk_f32_fp8(x3.x, false);
    a23 += wv3 * __builtin_amdgcn_cvt_pk_f32_fp8(x3.x, true);
    a45 += wv3 * __builtin_amdgcn_cvt_pk_f32_fp8(x3.y, false);
    a67 += wv3 * __builtin_amdgcn_cvt_pk_f32_fp8(x3.y, true);
  }
  float inv = (degw == 0.f) ? 1.f : 1.f / degw;
  m0 = a01.x * inv; m1 = a01.y * inv; m2 = a23.x * inv; m3 = a23.y * inv;
  m4 = a45.x * inv; m5 = a45.y * inv; m6 = a67.x * inv; m7 = a67.y * inv;
}

// ---- gather + relation attention: agg[node] = c1*mA + c2*mB (bf16) ----
// one 32-lane group per node (8 nodes / 256-block); group holds all 256 dims.
__global__ __launch_bounds__(256) void gatherAtt_kernel(GATab T) {
  const int bx = blockIdx.x;
  int t = 0;
#pragma unroll
  for (int k = 1; k < 3; ++k) t += (bx >= T.cum[k]);
  const int node = (bx - T.cum[t]) * 8 + (threadIdx.x >> 5);
  const int c8 = threadIdx.x & 31;

  float mA0, mA1, mA2, mA3, mA4, mA5, mA6, mA7;
  float mB0, mB1, mB2, mB3, mB4, mB5, mB6, mB7;
  bucket_msg(T.swA[t], T.hpA[t], T.poA[t][node], T.peA[t][node], c8,
             mA0, mA1, mA2, mA3, mA4, mA5, mA6, mA7);
  bucket_msg(T.swB[t], T.hpB[t], T.poB[t][node], T.peB[t][node], c8,
             mB0, mB1, mB2, mB3, mB4, mB5, mB6, mB7);

  // attention: scores via in-register dots + intra-group shfl reduce, then softmax
  const float4* A1v = reinterpret_cast<const float4*>(T.A1[t]);  // [4][64] float4
  const float4* A2v = reinterpret_cast<const float4*>(T.A2[t]);
  float c1 = 0.f, c2 = 0.f;
#pragma unroll
  for (int hh = 0; hh < 4; ++hh) {
    float4 qa = A1v[hh * 64 + c8 * 2], qb = A1v[hh * 64 + c8 * 2 + 1];
    float4 ra = A2v[hh * 64 + c8 * 2], rb = A2v[hh * 64 + c8 * 2 + 1];
    float sA = mA0 * qa.x + mA1 * qa.y + mA2 * qa.z + mA3 * qa.w
             + mA4 * qb.x + mA5 * qb.y + mA6 * qb.z + mA7 * qb.w;
    float sB = mB0 * ra.x + mB1 * ra.y + mB2 * ra.z + mB3 * ra.w
             + mB4 * rb.x + mB5 * rb.y + mB6 * rb.z + mB7 * rb.w;
#pragma unroll
    for (int o = 1; o <= 16; o <<= 1) { sA += __shfl_xor(sA, o); sB += __shfl_xor(sB, o); }
    // softmax over the 2 relations; scale = 1/(sqrt(256)*0.5) = 0.125
    float s1 = sA * 0.125f, s2 = sB * 0.125f;
    float mx = fmaxf(s1, s2);
    float e1 = __expf(s1 - mx), e2 = __expf(s2 - mx);
    float inv = 1.f / (e1 + e2);
    c1 += e1 * inv; c2 += e2 * inv;
  }
  c1 *= 0.25f; c2 *= 0.25f;  // mean over H=4 heads

  u32x4 o;
  o.x = (unsigned)f2bf(c1 * mA0 + c2 * mB0) | ((unsigned)f2bf(c1 * mA1 + c2 * mB1) << 16);
  o.y = (unsigned)f2bf(c1 * mA2 + c2 * mB2) | ((unsigned)f2bf(c1 * mA3 + c2 * mB3) << 16);
  o.z = (unsigned)f2bf(c1 * mA4 + c2 * mB4) | ((unsigned)f2bf(c1 * mA5 + c2 * mB5) << 16);
  o.w = (unsigned)f2bf(c1 * mA6 + c2 * mB6) | ((unsigned)f2bf(c1 * mA7 + c2 * mB7) << 16);
  __builtin_nontemporal_store(o, reinterpret_cast<u32x4*>(T.agg[t]) + (size_t)node * 32 + c8);
}

// ---- all 3 types merged: self-GEMM + agg + residual + LN + leaky (rounds 15-18 proven) ----
__global__ __launch_bounds__(256) void fuse3_kernel(FTab F) {
  __shared__ alignas(16) union SM {
    struct { unsigned short x[64 * 264]; unsigned short w[256 * 56]; } g;
    unsigned short s[64 * 260];  // self result, bf16
  } ov;
  __shared__ float sgb[512];
  const int tid = threadIdx.x;
  const int bx = blockIdx.x;
  int t = 0;
#pragma unroll
  for (int k = 1; k < 3; ++k) t += (bx >= F.cum[k]);
  const int r0 = (bx - F.cum[t]) * 64;
  const float* __restrict__ h = F.h[t];
  const unsigned short* __restrict__ agg = F.agg[t];

  stage_x_f32(h, r0, ov.g.x, tid);
  for (int i = tid; i < 512; i += 256) sgb[i] = (i < 256) ? F.gm[t][i] : F.bt[t][i - 256];

  f32x4 accv[4][4];
#pragma unroll
  for (int a = 0; a < 4; ++a)
#pragma unroll
    for (int b = 0; b < 4; ++b) accv[a][b] = {0.f, 0.f, 0.f, 0.f};

  gemm_frag(ov.g.x, F.wbf[t], ov.g.w, tid, accv);

  const int wid = tid >> 6, lane = tid & 63, lhi = lane >> 4, llo = lane & 15;
  __syncthreads();  // all MFMA LDS reads done before overlaying ov.s
#pragma unroll
  for (int rt = 0; rt < 4; ++rt)
#pragma unroll
    for (int nt = 0; nt < 4; ++nt) {
      int col = wid * 64 + nt * 16 + llo;
#pragma unroll
      for (int rg = 0; rg < 4; ++rg)
        ov.s[(rt * 16 + lhi * 4 + rg) * 260 + col] = f2bf(accv[rt][nt][rg]);
    }
  __syncthreads();

  // epilogue: wave handles 16 rows; lane owns 4 dims
  const int d0 = lane * 4;
  const float4 g4 = *reinterpret_cast<const float4*>(&sgb[d0]);
  const float4 b4 = *reinterpret_cast<const float4*>(&sgb[256 + d0]);
  float* __restrict__ outp = F.out[t];

  for (int rl = 0; rl < 16; ++rl) {
    int row = wid * 16 + rl;
    size_t gb = (size_t)(r0 + row) * DIM + d0;
    ushort4 ab = *reinterpret_cast<const ushort4*>(agg + gb);
    float4 av = {bf2f(ab.x), bf2f(ab.y), bf2f(ab.z), bf2f(ab.w)};
    float4 hvv = *reinterpret_cast<const float4*>(h + gb);
    ushort4 sb = *reinterpret_cast<const ushort4*>(&ov.s[row * 260 + d0]);
    float4 sv = {bf2f(sb.x), bf2f(sb.y), bf2f(sb.z), bf2f(sb.w)};

    float4 u;
    u.x = sv.x + av.x + hvv.x;
    u.y = sv.y + av.y + hvv.y;
    u.z = sv.z + av.z + hvv.z;
    u.w = sv.w + av.w + hvv.w;

    float s1v = u.x + u.y + u.z + u.w;
    float s2v = u.x * u.x + u.y * u.y + u.z * u.z + u.w * u.w;
#pragma unroll
    for (int o = 1; o < 64; o <<= 1) { s1v += __shfl_xor(s1v, o); s2v += __shfl_xor(s2v, o); }
    float mu = s1v * (1.f / 256.f);
    float var = s2v * (1.f / 256.f) - mu * mu;
    float rstd = rsqrtf(var + 1e-5f);

    float4 y;
    y.x = (u.x - mu) * rstd * g4.x + b4.x;
    y.y = (u.y - mu) * rstd * g4.y + b4.y;
    y.z = (u.z - mu) * rstd * g4.z + b4.z;
    y.w = (u.w - mu) * rstd * g4.w + b4.w;
    y.x = fmaxf(y.x, 0.01f * y.x);
    y.y = fmaxf(y.y, 0.01f * y.y);
    y.z = fmaxf(y.z, 0.01f * y.z);
    y.w = fmaxf(y.w, 0.01f * y.w);
    *reinterpret_cast<float4*>(outp + gb) = y;
  }
}

// ---- workspace layout (bytes); ~88 MB (< proven ~139 MB) ----
static constexpr size_t AL(size_t x) { return (x + 255) & ~size_t(255); }
// aggregated messages (bf16), one row per node, type-major l|g|d
static constexpr size_t AGG_TOT = (size_t)(NLr + NGr + NDr) * DIM;      // ushorts
// transformed embeddings (fp8, 1 byte/elem), all 6 relations, sized by SRC rows
static constexpr size_t HPe_L2G = 0;                                    // NLr rows
static constexpr size_t HPe_G2L = HPe_L2G + (size_t)NLr * DIM;          // NGr
static constexpr size_t HPe_G2D = HPe_G2L + (size_t)NGr * DIM;          // NGr
static constexpr size_t HPe_D2G = HPe_G2D + (size_t)NGr * DIM;          // NDr
static constexpr size_t HPe_L2D = HPe_D2G + (size_t)NDr * DIM;          // NLr
static constexpr size_t HPe_D2L = HPe_L2D + (size_t)NLr * DIM;          // NDr
static constexpr size_t HP_TOT  = HPe_D2L + (size_t)NDr * DIM;          // bytes
static constexpr size_t OFF_AGG   = 0;
static constexpr size_t OFF_HP    = AL(OFF_AGG + AGG_TOT * 2);
static constexpr size_t OFF_WBF   = AL(OFF_HP + HP_TOT);
static constexpr size_t OFF_POFF  = AL(OFF_WBF + 9 * 65536 * 2);        // 6*HSTRIDE ints
static constexpr size_t OFF_PEND  = AL(OFF_POFF + 6 * HSTRIDE * 4);     // 6*HSTRIDE ints
static constexpr size_t OFF_CHIST = AL(OFF_PEND + 6 * HSTRIDE * 4);     // 384 ints
static constexpr size_t OFF_CBASE = AL(OFF_CHIST + 384 * 4);            // 6*65 ints
static constexpr size_t OFF_PBASE = AL(OFF_CBASE + 390 * 4);            // 6*65 ints
static constexpr size_t OFF_CCUR  = AL(OFF_PBASE + 390 * 4);            // 384 ints
static constexpr size_t OFF_TMP   = AL(OFF_CCUR + 384 * 4);             // 6*NE int2
static constexpr size_t OFF_SRCW  = AL(OFF_TMP + (size_t)6 * NE * 8);   // 6*PADNE u32

extern "C" void kernel_launch(void* const* d_in, const int* in_sizes, int n_in,
                              void* d_out, int out_size, void* d_ws, size_t ws_size,
                              hipStream_t stream) {
  char* wsb = (char*)d_ws;
  unsigned short* agg = (unsigned short*)(wsb + OFF_AGG);
  unsigned char* hp   = (unsigned char*)(wsb + OFF_HP);
  unsigned short* wbf = (unsigned short*)(wsb + OFF_WBF);
  int* poffs = (int*)(wsb + OFF_POFF);
  int* pends = (int*)(wsb + OFF_PEND);
  int* chist = (int*)(wsb + OFF_CHIST);
  int* cbase = (int*)(wsb + OFF_CBASE);
  int* pbase = (int*)(wsb + OFF_PBASE);
  int* ccur  = (int*)(wsb + OFF_CCUR);
  int2* tmp  = (int2*)(wsb + OFF_TMP);
  unsigned* srcw = (unsigned*)(wsb + OFF_SRCW);
  float* out = (float*)d_out;

  // relation order: l2g, g2l, g2d, d2g, l2d, d2l
  const int base[6] = {3, 8, 13, 18, 23, 28};
  const int ndst[6] = {NGr, NLr, NDr, NGr, NDr, NLr};
  const size_t hpOff[6]  = {HPe_L2G, HPe_G2L, HPe_G2D, HPe_D2G, HPe_L2D, HPe_D2L};

  // merged prep: weight f32->bf16 + coarse dst histogram
  (void)hipMemsetAsync(chist, 0, 384 * 4, stream);
  PrepTab Q; PTab P; NTab N;
  Q.wsrc[0] = (const float*)d_in[6];  Q.wsrc[1] = (const float*)d_in[11];
  Q.wsrc[2] = (const float*)d_in[16]; Q.wsrc[3] = (const float*)d_in[21];
  Q.wsrc[4] = (const float*)d_in[26]; Q.wsrc[5] = (const float*)d_in[31];
  Q.wsrc[6] = (const float*)d_in[33]; Q.wsrc[7] = (const float*)d_in[36];
  Q.wsrc[8] = (const float*)d_in[39];
  for (int r = 0; r < 6; ++r) {
    int sh = (ndst[r] == NGr) ? 9 : (ndst[r] == NLr ? 8 : 7);  // coarse = n>>6
    Q.dst[r] = (const int*)d_in[base[r] + 1];
    Q.shift[r] = sh;
    P.src[r] = (const int*)d_in[base[r]];
    P.dst[r] = (const int*)d_in[base[r] + 1];
    P.w[r]  = (const float*)d_in[base[r] + 2];
    P.shift[r] = sh;
    N.n[r] = ndst[r];
  }
  prep_kernel<<<2304 + 1536, 256, 0, stream>>>(Q, wbf, chist);
  scan384_kernel<<<1, 64, 0, stream>>>(chist, ccur, cbase, pbase, N);

  // partition pass A (coarse)
  partA6_kernel<<<dim3(NE / 1024, 6), 256, 0, stream>>>(P, ccur, tmp);

  // mid: partB (padded fine placement + poffs/pends) OVERLAPPED with transformT
  // type l -> {l2g(0), l2d(4)}, type g -> {g2l(1), g2d(2)}, type d -> {d2g(3), d2l(5)}
  TTy T;
  T.h[0] = (const float*)d_in[0]; T.h[1] = (const float*)d_in[1]; T.h[2] = (const float*)d_in[2];
  T.hpA[0] = hp + hpOff[0]; T.hpB[0] = hp + hpOff[4];
  T.hpA[1] = hp + hpOff[1]; T.hpB[1] = hp + hpOff[2];
  T.hpA[2] = hp + hpOff[3]; T.hpB[2] = hp + hpOff[5];
  T.wA[0] = wbf + 0 * 65536; T.wB[0] = wbf + 4 * 65536;
  T.wA[1] = wbf + 1 * 65536; T.wB[1] = wbf + 2 * 65536;
  T.wA[2] = wbf + 3 * 65536; T.wB[2] = wbf + 5 * 65536;
  T.cum[0] = 0; T.cum[1] = NLr / 64; T.cum[2] = (NLr + NGr) / 64; T.cum[3] = (NLr + NGr + NDr) / 64;
  mid_kernel<<<384 + 896, 256, 0, stream>>>(tmp, cbase, pbase, poffs, pends, srcw, N, T);

  // gather + attention per dest type: l <- {g2l(1), d2l(5)}, g <- {l2g(0), d2g(3)},
  // d <- {g2d(2), l2d(4)}; one 32-lane group per node (padded fp8 rows)
  GATab G;
  const int relA[3] = {1, 0, 2}, relB[3] = {5, 3, 4};
  const int aA[3] = {12, 7, 17}, aB[3] = {32, 22, 27};
  const size_t aggBase[3] = {0, (size_t)NLr * DIM, (size_t)(NLr + NGr) * DIM};
  for (int t = 0; t < 3; ++t) {
    G.hpA[t] = hp + hpOff[relA[t]];
    G.hpB[t] = hp + hpOff[relB[t]];
    G.swA[t] = srcw + (size_t)relA[t] * PADNE;
    G.swB[t] = srcw + (size_t)relB[t] * PADNE;
    G.poA[t] = poffs + relA[t] * HSTRIDE;
    G.peA[t] = pends + relA[t] * HSTRIDE;
    G.poB[t] = poffs + relB[t] * HSTRIDE;
    G.peB[t] = pends + relB[t] * HSTRIDE;
    G.A1[t] = (const float*)d_in[aA[t]];
    G.A2[t] = (const float*)d_in[aB[t]];
    G.agg[t] = agg + aggBase[t];
  }
  G.cum[0] = 0; G.cum[1] = NLr / 8; G.cum[2] = (NLr + NGr) / 8; G.cum[3] = (NLr + NGr + NDr) / 8;
  gatherAtt_kernel<<<G.cum[3], 256, 0, stream>>>(G);

  // fused update, all 3 types in one launch
  FTab F;
  F.h[0] = (const float*)d_in[0]; F.h[1] = (const float*)d_in[1]; F.h[2] = (const float*)d_in[2];
  F.agg[0] = agg + aggBase[0]; F.agg[1] = agg + aggBase[1]; F.agg[2] = agg + aggBase[2];
  F.wbf[0] = wbf + 6 * 65536; F.wbf[1] = wbf + 7 * 65536; F.wbf[2] = wbf + 8 * 65536;
  F.gm[0] = (const float*)d_in[34]; F.bt[0] = (const float*)d_in[35];
  F.gm[1] = (const float*)d_in[37]; F.bt[1] = (const float*)d_in[38];
  F.gm[2] = (const float*)d_in[40]; F.bt[2] = (const float*)d_in[41];
  F.out[0] = out;
  F.out[1] = out + (size_t)NLr * DIM;
  F.out[2] = out + (size_t)(NLr + NGr) * DIM;
  F.cum[0] = 0; F.cum[1] = NLr / 64; F.cum[2] = (NLr + NGr) / 64; F.cum[3] = (NLr + NGr + NDr) / 64;
  fuse3_kernel<<<F.cum[3], 256, 0, stream>>>(F);
}

// Round 21
// 233.029 us; speedup vs baseline: 1.1633x; 1.0041x over previous
//
#include <hip/hip_runtime.h>

#define DIM 256
#define NLr 16384
#define NGr 32768
#define NDr 8192
#define NE  262144
#define PADNE 524288   // padded srcw stride: NE + 8*max_n
#define HSTRIDE 32772  // poffs/pends per-relation stride (16B-aligned)

typedef short bf16x8 __attribute__((ext_vector_type(8)));
typedef float f32x4 __attribute__((ext_vector_type(4)));
typedef float f32x2 __attribute__((ext_vector_type(2)));
typedef unsigned u32x4 __attribute__((ext_vector_type(4)));

__device__ __forceinline__ unsigned short f2bf(float f) {
  unsigned int u = __builtin_bit_cast(unsigned int, f);
  u += 0x7fffu + ((u >> 16) & 1u);
  return (unsigned short)(u >> 16);
}
__device__ __forceinline__ float bf2f(unsigned short b) {
  return __builtin_bit_cast(float, ((unsigned int)b) << 16);
}
__device__ __forceinline__ float bfhi(unsigned int u) {
  return __builtin_bit_cast(float, u & 0xffff0000u);
}

struct NTab { int n[6]; };
struct PrepTab { const float* wsrc[9]; const int* dst[6]; int shift[6]; };
struct PTab { const int* src[6]; const int* dst[6]; const float* w[6]; int shift[6]; };
struct TTy { const float* h[3]; unsigned char* hpA[3]; unsigned char* hpB[3];
             const unsigned short* wA[3]; const unsigned short* wB[3]; int cum[4]; };
struct GATab { const unsigned char* hpA[3]; const unsigned char* hpB[3];
               const unsigned* swA[3]; const unsigned* swB[3];
               const int* poA[3]; const int* peA[3];
               const int* poB[3]; const int* peB[3];
               const float* A1[3]; const float* A2[3];
               unsigned short* agg[3]; int cum[4]; };
struct FTab { const float* h[3]; const unsigned short* agg[3];
              const unsigned short* wbf[3]; const float* gm[3]; const float* bt[3];
              float* out[3]; int cum[4]; };

// ---- merged prep: blocks [0,2304) convert 9 weight mats; [2304,3840) coarse hist ----
__global__ __launch_bounds__(256) void prep_kernel(PrepTab Q, unsigned short* __restrict__ wbf,
                                                   int* __restrict__ chist) {
  const int bid = blockIdx.x, tid = threadIdx.x;
  __shared__ int h[64];
  if (bid < 2304) {
    int m = bid >> 8;
    int i = (bid & 255) * 256 + tid;
    wbf[m * 65536 + i] = f2bf(Q.wsrc[m][i]);
  } else {
    int b2 = bid - 2304;
    int r = b2 >> 8;          // 256 blocks per relation, 1024 edges each
    int blk = b2 & 255;
    if (tid < 64) h[tid] = 0;
    __syncthreads();
    const int* dp = Q.dst[r] + blk * 1024;
    const int sh = Q.shift[r];
#pragma unroll
    for (int k = 0; k < 4; ++k) atomicAdd(&h[dp[k * 256 + tid] >> sh], 1);
    __syncthreads();
    if (tid < 64) { int c = h[tid]; if (c) atomicAdd(&chist[r * 64 + tid], c); }
  }
}

// ---- tiny coarse scan: ccur (partA cursor), cbase (tmp windows), pbase (padded srcw) ----
__global__ void scan384_kernel(const int* __restrict__ chist, int* __restrict__ ccur,
                               int* __restrict__ cbase, int* __restrict__ pbase, NTab N) {
  int r = threadIdx.x;
  if (r < 6) {
    int off = 0, offp = 0;
    int s8 = (N.n[r] >> 6) * 8;   // per-window pad slack
    for (int b = 0; b < 64; ++b) {
      ccur[r * 64 + b] = off;
      cbase[r * 65 + b] = off;
      pbase[r * 65 + b] = offp;
      off += chist[r * 64 + b];
      offp += chist[r * 64 + b] + s8;
    }
    cbase[r * 65 + 64] = off;  // == NE
  }
}

// ---- partition pass A: coarse 64-bucket partition into tmp (dst, packed) ----
__global__ __launch_bounds__(256) void partA6_kernel(PTab P, int* __restrict__ ccur,
                                                     int2* __restrict__ tmp) {
  int r = blockIdx.y;
  const int tid = threadIdx.x;
  __shared__ int hist[64], lbase[64], lcur[64];
  if (tid < 64) { hist[tid] = 0; lcur[tid] = 0; }
  __syncthreads();
  const int ebase = blockIdx.x * 1024;
  const int sh = P.shift[r];
  int dsts[4]; unsigned pk[4]; int bks[4];
#pragma unroll
  for (int k = 0; k < 4; ++k) {
    int e = ebase + k * 256 + tid;
    int d = P.dst[r][e];
    dsts[k] = d;
    pk[k] = (unsigned)P.src[r][e] | ((unsigned)f2bf(P.w[r][e]) << 16);
    bks[k] = d >> sh;
    atomicAdd(&hist[bks[k]], 1);
  }
  __syncthreads();
  if (tid < 64) {
    int c = hist[tid];
    if (c) lbase[tid] = atomicAdd(&ccur[r * 64 + tid], c);
  }
  __syncthreads();
#pragma unroll
  for (int k = 0; k < 4; ++k) {
    int pos = lbase[bks[k]] + atomicAdd(&lcur[bks[k]], 1);
    tmp[(size_t)r * NE + pos] = make_int2(dsts[k], (int)pk[k]);
  }
}

// ---- shared GEMM pieces: 64 rows x (256x256) bf16 MFMA (rounds 6-18 proven) ----
__device__ __forceinline__ void stage_x_f32(const float* __restrict__ g, int r0,
                                            unsigned short* xs, int tid) {
#pragma unroll
  for (int it = 0; it < 16; ++it) {
    int i = it * 256 + tid;
    int row = i >> 6, q = i & 63;
    float4 v = reinterpret_cast<const float4*>(g)[(size_t)(r0 + row) * 64 + q];
    ushort4 b;
    b.x = f2bf(v.x); b.y = f2bf(v.y); b.z = f2bf(v.z); b.w = f2bf(v.w);
    *reinterpret_cast<ushort4*>(&xs[row * 264 + q * 4]) = b;
  }
}

__device__ __forceinline__ void gemm_frag(const unsigned short* xs,
                                          const unsigned short* __restrict__ Wg,
                                          unsigned short* wl, int tid,
                                          f32x4 accv[4][4]) {
  const int wid = tid >> 6, lhi = (tid & 63) >> 4, llo = tid & 15;
  for (int ks = 0; ks < 8; ++ks) {
    const int k0 = ks * 32;
    __syncthreads();  // protects xs (first iter) and wl reads from prev iter
    {
      const uint4* gp = reinterpret_cast<const uint4*>(Wg + (size_t)tid * 256 + k0);
      uint4 a0 = gp[0], a1 = gp[1], a2 = gp[2], a3 = gp[3];
      uint4* lp = reinterpret_cast<uint4*>(wl + tid * 56);
      lp[0] = a0; lp[1] = a1; lp[2] = a2; lp[3] = a3;
    }
    __syncthreads();
    bf16x8 afr[4], bfr[4];
#pragma unroll
    for (int rt = 0; rt < 4; ++rt)
      afr[rt] = *reinterpret_cast<const bf16x8*>(&xs[(rt * 16 + llo) * 264 + k0 + lhi * 8]);
#pragma unroll
    for (int nt = 0; nt < 4; ++nt)
      bfr[nt] = *reinterpret_cast<const bf16x8*>(&wl[(wid * 64 + nt * 16 + llo) * 56 + lhi * 8]);
#pragma unroll
    for (int rt = 0; rt < 4; ++rt)
#pragma unroll
      for (int nt = 0; nt < 4; ++nt)
        accv[rt][nt] = __builtin_amdgcn_mfma_f32_16x16x32_bf16(afr[rt], bfr[nt], accv[rt][nt], 0, 0, 0);
  }
}

// ---- writeout: accv -> fp8 e4m3 bytes (hp row = 256 B) ----
__device__ __forceinline__ void writeout_hp(unsigned char* __restrict__ hp, int r0, int tid,
                                            f32x4 accv[4][4]) {
  const int wid = tid >> 6, lane = tid & 63, lhi = lane >> 4, llo = lane & 15;
#pragma unroll
  for (int rt = 0; rt < 4; ++rt)
#pragma unroll
    for (int nt = 0; nt < 4; ++nt) {
      int col = wid * 64 + nt * 16 + llo;
#pragma unroll
      for (int rg = 0; rg < 4; ++rg) {
        int row = rt * 16 + lhi * 4 + rg;
        int pk = __builtin_amdgcn_cvt_pk_fp8_f32(accv[rt][nt][rg], accv[rt][nt][rg], 0, false);
        hp[(size_t)(r0 + row) * DIM + col] = (unsigned char)(pk & 0xff);
      }
    }
}

// ---- mid kernel: partB (blocks [0,384)) ∥ transformT (blocks [384,1280)) ----
// partB emits PADDED buckets (pend-pstart = ceil(cnt/8)*8, pads zero-filled).
__global__ __launch_bounds__(256) void mid_kernel(const int2* __restrict__ tmp,
                                                  const int* __restrict__ cbase,
                                                  const int* __restrict__ pbase,
                                                  int* __restrict__ poffs,
                                                  int* __restrict__ pends,
                                                  unsigned* __restrict__ srcw,
                                                  NTab N, TTy T) {
  __shared__ union alignas(16) SM {
    struct { unsigned short xs[64 * 264]; unsigned short wl[256 * 56]; } t;
    struct { int hist[512]; int part[256]; int pend[512]; } p;
  } sm;
  const int bid = blockIdx.x, tid = threadIdx.x;

  if (bid < 384) {
    // ---------------- partB path (padded placement) ----------------
    int r = bid >> 6, b = bid & 63;
    const int n = N.n[r], s = n >> 6;
    const int dbase = b * s;
    int* hist = sm.p.hist;
    int* part = sm.p.part;
    int* pendL = sm.p.pend;
    for (int i = tid; i < s; i += 256) hist[i] = 0;
    __syncthreads();
    const int wbeg = cbase[r * 65 + b], wend = cbase[r * 65 + b + 1];
    const int2* __restrict__ tr = tmp + (size_t)r * NE;
    for (int i = wbeg + tid; i < wend; i += 256)
      atomicAdd(&hist[tr[i].x - dbase], 1);
    __syncthreads();
    const int per = (s > 256) ? 2 : 1;
    const int base = tid * per;
    int pv[2];
    int mysum = 0;
#pragma unroll
    for (int j = 0; j < 2; ++j) {
      int idx = base + j;
      int cnt = (j < per && idx < s) ? hist[idx] : 0;
      pv[j] = (cnt + 7) & ~7;          // padded bucket length
      mysum += pv[j];
    }
    part[tid] = mysum;
    __syncthreads();
    for (int off = 1; off < 256; off <<= 1) {
      int v = (tid >= off) ? part[tid - off] : 0;
      __syncthreads();
      part[tid] += v;
      __syncthreads();
    }
    int run = part[tid] - mysum + pbase[r * 65 + b];
#pragma unroll
    for (int j = 0; j < 2; ++j) {
      int idx = base + j;
      if (j < per && idx < s) {
        hist[idx] = run;                               // live cursor (real entries)
        pendL[idx] = run + pv[j];
        poffs[r * HSTRIDE + dbase + idx] = run;        // padded start
        pends[r * HSTRIDE + dbase + idx] = run + pv[j];// padded end
        run += pv[j];
      }
    }
    __syncthreads();
    unsigned* __restrict__ swr = srcw + (size_t)r * PADNE;
    for (int i = wbeg + tid; i < wend; i += 256) {
      int2 e = tr[i];
      int pos = atomicAdd(&hist[e.x - dbase], 1);
      swr[pos] = (unsigned)e.y;
    }
    __syncthreads();
    // zero-fill pad slots (src=0, w=+0.0 -> exact no-op in gather)
    for (int i = tid; i < s; i += 256)
      for (int p = hist[i]; p < pendL[i]; ++p) swr[p] = 0u;
  } else {
    // ---------------- transformT path (fp8 writeout) ----------------
    const int bx = bid - 384;
    int t = 0;
#pragma unroll
    for (int k = 1; k < 3; ++k) t += (bx >= T.cum[k]);
    const int r0 = (bx - T.cum[t]) * 64;

    stage_x_f32(T.h[t], r0, sm.t.xs, tid);

    f32x4 accv[4][4];
#pragma unroll
    for (int a = 0; a < 4; ++a)
#pragma unroll
      for (int b2 = 0; b2 < 4; ++b2) accv[a][b2] = {0.f, 0.f, 0.f, 0.f};
    gemm_frag(sm.t.xs, T.wA[t], sm.t.wl, tid, accv);
    writeout_hp(T.hpA[t], r0, tid, accv);

#pragma unroll
    for (int a = 0; a < 4; ++a)
#pragma unroll
      for (int b2 = 0; b2 < 4; ++b2) accv[a][b2] = {0.f, 0.f, 0.f, 0.f};
    gemm_frag(sm.t.xs, T.wB[t], sm.t.wl, tid, accv);  // first barrier inside protects wl reuse
    writeout_hp(T.hpB[t], r0, tid, accv);
  }
}

// ---- bucket walk: fp8 rows, f32x2 math, guard-free (padded %8 -> %4), 32-lane group ----
__device__ __forceinline__ void bucket_msg(const unsigned* __restrict__ sw,
                                           const unsigned char* __restrict__ hp,
                                           int beg, int end, int c8,
                                           float& m0, float& m1, float& m2, float& m3,
                                           float& m4, float& m5, float& m6, float& m7) {
  f32x2 a01 = {0.f, 0.f}, a23 = {0.f, 0.f}, a45 = {0.f, 0.f}, a67 = {0.f, 0.f};
  float degw = 0.f;
  const int boff = c8 * 8;
  for (int j = beg; j < end; j += 4) {
    unsigned e0 = sw[j + 0], e1 = sw[j + 1], e2 = sw[j + 2], e3 = sw[j + 3];
    float w0 = bfhi(e0), w1 = bfhi(e1), w2 = bfhi(e2), w3 = bfhi(e3);
    uint2 x0 = *reinterpret_cast<const uint2*>(hp + (size_t)(e0 & 0xffff) * DIM + boff);
    uint2 x1 = *reinterpret_cast<const uint2*>(hp + (size_t)(e1 & 0xffff) * DIM + boff);
    uint2 x2 = *reinterpret_cast<const uint2*>(hp + (size_t)(e2 & 0xffff) * DIM + boff);
    uint2 x3 = *reinterpret_cast<const uint2*>(hp + (size_t)(e3 & 0xffff) * DIM + boff);
    degw += (w0 + w1) + (w2 + w3);
    f32x2 wv0 = {w0, w0}, wv1 = {w1, w1}, wv2 = {w2, w2}, wv3 = {w3, w3};
    a01 += wv0 * __builtin_amdgcn_cvt_pk_f32_fp8(x0.x, false);
    a23 += wv0 * __builtin_amdgcn_cvt_pk_f32_fp8(x0.x, true);
    a45 += wv0 * __builtin_amdgcn_cvt_pk_f32_fp8(x0.y, false);
    a67 += wv0 * __builtin_amdgcn_cvt_pk_f32_fp8(x0.y, true);
    a01 += wv1 * __builtin_amdgcn_cvt_pk_f32_fp8(x1.x, false);
    a23 += wv1 * __builtin_amdgcn_cvt_pk_f32_fp8(x1.x, true);
    a45 += wv1 * __builtin_amdgcn_cvt_pk_f32_fp8(x1.y, false);
    a67 += wv1 * __builtin_amdgcn_cvt_pk_f32_fp8(x1.y, true);
    a01 += wv2 * __builtin_amdgcn_cvt_pk_f32_fp8(x2.x, false);
    a23 += wv2 * __builtin_amdgcn_cvt_pk_f32_fp8(x2.x, true);
    a45 += wv2 * __builtin_amdgcn_cvt_pk_f32_fp8(x2.y, false);
    a67 += wv2 * __builtin_amdgcn_cvt_pk_f32_fp8(x2.y, true);
    a01 += wv3 * __builtin_amdgcn_cvt_pk_f32_fp8(x3.x, false);
    a23 += wv3 * __builtin_amdgcn_cvt_pk_f32_fp8(x3.x, true);
    a45 += wv3 * __builtin_amdgcn_cvt_pk_f32_fp8(x3.y, false);
    a67 += wv3 * __builtin_amdgcn_cvt_pk_f32_fp8(x3.y, true);
  }
  float inv = (degw == 0.f) ? 1.f : 1.f / degw;
  m0 = a01.x * inv; m1 = a01.y * inv; m2 = a23.x * inv; m3 = a23.y * inv;
  m4 = a45.x * inv; m5 = a45.y * inv; m6 = a67.x * inv; m7 = a67.y * inv;
}

// ---- gather + relation attention: agg[node] = c1*mA + c2*mB (bf16) ----
// one 32-lane group per node (8 nodes / 256-block); group holds all 256 dims.
__global__ __launch_bounds__(256) void gatherAtt_kernel(GATab T) {
  const int bx = blockIdx.x;
  int t = 0;
#pragma unroll
  for (int k = 1; k < 3; ++k) t += (bx >= T.cum[k]);
  const int node = (bx - T.cum[t]) * 8 + (threadIdx.x >> 5);
  const int c8 = threadIdx.x & 31;

  float mA0, mA1, mA2, mA3, mA4, mA5, mA6, mA7;
  float mB0, mB1, mB2, mB3, mB4, mB5, mB6, mB7;
  bucket_msg(T.swA[t], T.hpA[t], T.poA[t][node], T.peA[t][node], c8,
             mA0, mA1, mA2, mA3, mA4, mA5, mA6, mA7);
  bucket_msg(T.swB[t], T.hpB[t], T.poB[t][node], T.peB[t][node], c8,
             mB0, mB1, mB2, mB3, mB4, mB5, mB6, mB7);

  // attention: scores via in-register dots + intra-group shfl reduce, then softmax
  const float4* A1v = reinterpret_cast<const float4*>(T.A1[t]);  // [4][64] float4
  const float4* A2v = reinterpret_cast<const float4*>(T.A2[t]);
  float c1 = 0.f, c2 = 0.f;
#pragma unroll
  for (int hh = 0; hh < 4; ++hh) {
    float4 qa = A1v[hh * 64 + c8 * 2], qb = A1v[hh * 64 + c8 * 2 + 1];
    float4 ra = A2v[hh * 64 + c8 * 2], rb = A2v[hh * 64 + c8 * 2 + 1];
    float sA = mA0 * qa.x + mA1 * qa.y + mA2 * qa.z + mA3 * qa.w
             + mA4 * qb.x + mA5 * qb.y + mA6 * qb.z + mA7 * qb.w;
    float sB = mB0 * ra.x + mB1 * ra.y + mB2 * ra.z + mB3 * ra.w
             + mB4 * rb.x + mB5 * rb.y + mB6 * rb.z + mB7 * rb.w;
#pragma unroll
    for (int o = 1; o <= 16; o <<= 1) { sA += __shfl_xor(sA, o); sB += __shfl_xor(sB, o); }
    // softmax over the 2 relations; scale = 1/(sqrt(256)*0.5) = 0.125
    float s1 = sA * 0.125f, s2 = sB * 0.125f;
    float mx = fmaxf(s1, s2);
    float e1 = __expf(s1 - mx), e2 = __expf(s2 - mx);
    float inv = 1.f / (e1 + e2);
    c1 += e1 * inv; c2 += e2 * inv;
  }
  c1 *= 0.25f; c2 *= 0.25f;  // mean over H=4 heads

  u32x4 o;
  o.x = (unsigned)f2bf(c1 * mA0 + c2 * mB0) | ((unsigned)f2bf(c1 * mA1 + c2 * mB1) << 16);
  o.y = (unsigned)f2bf(c1 * mA2 + c2 * mB2) | ((unsigned)f2bf(c1 * mA3 + c2 * mB3) << 16);
  o.z = (unsigned)f2bf(c1 * mA4 + c2 * mB4) | ((unsigned)f2bf(c1 * mA5 + c2 * mB5) << 16);
  o.w = (unsigned)f2bf(c1 * mA6 + c2 * mB6) | ((unsigned)f2bf(c1 * mA7 + c2 * mB7) << 16);
  __builtin_nontemporal_store(o, reinterpret_cast<u32x4*>(T.agg[t]) + (size_t)node * 32 + c8);
}

// ---- all 3 types merged: self-GEMM + agg + residual + LN + leaky (rounds 15-18 proven) ----
__global__ __launch_bounds__(256) void fuse3_kernel(FTab F) {
  __shared__ alignas(16) union SM {
    struct { unsigned short x[64 * 264]; unsigned short w[256 * 56]; } g;
    unsigned short s[64 * 260];  // self result, bf16
  } ov;
  __shared__ float sgb[512];
  const int tid = threadIdx.x;
  const int bx = blockIdx.x;
  int t = 0;
#pragma unroll
  for (int k = 1; k < 3; ++k) t += (bx >= F.cum[k]);
  const int r0 = (bx - F.cum[t]) * 64;
  const float* __restrict__ h = F.h[t];
  const unsigned short* __restrict__ agg = F.agg[t];

  stage_x_f32(h, r0, ov.g.x, tid);
  for (int i = tid; i < 512; i += 256) sgb[i] = (i < 256) ? F.gm[t][i] : F.bt[t][i - 256];

  f32x4 accv[4][4];
#pragma unroll
  for (int a = 0; a < 4; ++a)
#pragma unroll
    for (int b = 0; b < 4; ++b) accv[a][b] = {0.f, 0.f, 0.f, 0.f};

  gemm_frag(ov.g.x, F.wbf[t], ov.g.w, tid, accv);

  const int wid = tid >> 6, lane = tid & 63, lhi = lane >> 4, llo = lane & 15;
  __syncthreads();  // all MFMA LDS reads done before overlaying ov.s
#pragma unroll
  for (int rt = 0; rt < 4; ++rt)
#pragma unroll
    for (int nt = 0; nt < 4; ++nt) {
      int col = wid * 64 + nt * 16 + llo;
#pragma unroll
      for (int rg = 0; rg < 4; ++rg)
        ov.s[(rt * 16 + lhi * 4 + rg) * 260 + col] = f2bf(accv[rt][nt][rg]);
    }
  __syncthreads();

  // epilogue: wave handles 16 rows; lane owns 4 dims
  const int d0 = lane * 4;
  const float4 g4 = *reinterpret_cast<const float4*>(&sgb[d0]);
  const float4 b4 = *reinterpret_cast<const float4*>(&sgb[256 + d0]);
  float* __restrict__ outp = F.out[t];

  for (int rl = 0; rl < 16; ++rl) {
    int row = wid * 16 + rl;
    size_t gb = (size_t)(r0 + row) * DIM + d0;
    ushort4 ab = *reinterpret_cast<const ushort4*>(agg + gb);
    float4 av = {bf2f(ab.x), bf2f(ab.y), bf2f(ab.z), bf2f(ab.w)};
    float4 hvv = *reinterpret_cast<const float4*>(h + gb);
    ushort4 sb = *reinterpret_cast<const ushort4*>(&ov.s[row * 260 + d0]);
    float4 sv = {bf2f(sb.x), bf2f(sb.y), bf2f(sb.z), bf2f(sb.w)};

    float4 u;
    u.x = sv.x + av.x + hvv.x;
    u.y = sv.y + av.y + hvv.y;
    u.z = sv.z + av.z + hvv.z;
    u.w = sv.w + av.w + hvv.w;

    float s1v = u.x + u.y + u.z + u.w;
    float s2v = u.x * u.x + u.y * u.y + u.z * u.z + u.w * u.w;
#pragma unroll
    for (int o = 1; o < 64; o <<= 1) { s1v += __shfl_xor(s1v, o); s2v += __shfl_xor(s2v, o); }
    float mu = s1v * (1.f / 256.f);
    float var = s2v * (1.f / 256.f) - mu * mu;
    float rstd = rsqrtf(var + 1e-5f);

    float4 y;
    y.x = (u.x - mu) * rstd * g4.x + b4.x;
    y.y = (u.y - mu) * rstd * g4.y + b4.y;
    y.z = (u.z - mu) * rstd * g4.z + b4.z;
    y.w = (u.w - mu) * rstd * g4.w + b4.w;
    y.x = fmaxf(y.x, 0.01f * y.x);
    y.y = fmaxf(y.y, 0.01f * y.y);
    y.z = fmaxf(y.z, 0.01f * y.z);
    y.w = fmaxf(y.w, 0.01f * y.w);
    *reinterpret_cast<float4*>(outp + gb) = y;
  }
}

// ---- workspace layout (bytes); ~88 MB (< proven ~139 MB) ----
static constexpr size_t AL(size_t x) { return (x + 255) & ~size_t(255); }
// aggregated messages (bf16), one row per node, type-major l|g|d
static constexpr size_t AGG_TOT = (size_t)(NLr + NGr + NDr) * DIM;      // ushorts
// transformed embeddings (fp8, 1 byte/elem), all 6 relations, sized by SRC rows
static constexpr size_t HPe_L2G = 0;                                    // NLr rows
static constexpr size_t HPe_G2L = HPe_L2G + (size_t)NLr * DIM;          // NGr
static constexpr size_t HPe_G2D = HPe_G2L + (size_t)NGr * DIM;          // NGr
static constexpr size_t HPe_D2G = HPe_G2D + (size_t)NGr * DIM;          // NDr
static constexpr size_t HPe_L2D = HPe_D2G + (size_t)NDr * DIM;          // NLr
static constexpr size_t HPe_D2L = HPe_L2D + (size_t)NLr * DIM;          // NDr
static constexpr size_t HP_TOT  = HPe_D2L + (size_t)NDr * DIM;          // bytes
static constexpr size_t OFF_AGG   = 0;
static constexpr size_t OFF_HP    = AL(OFF_AGG + AGG_TOT * 2);
static constexpr size_t OFF_WBF   = AL(OFF_HP + HP_TOT);
static constexpr size_t OFF_POFF  = AL(OFF_WBF + 9 * 65536 * 2);        // 6*HSTRIDE ints
static constexpr size_t OFF_PEND  = AL(OFF_POFF + 6 * HSTRIDE * 4);     // 6*HSTRIDE ints
static constexpr size_t OFF_CHIST = AL(OFF_PEND + 6 * HSTRIDE * 4);     // 384 ints
static constexpr size_t OFF_CBASE = AL(OFF_CHIST + 384 * 4);            // 6*65 ints
static constexpr size_t OFF_PBASE = AL(OFF_CBASE + 390 * 4);            // 6*65 ints
static constexpr size_t OFF_CCUR  = AL(OFF_PBASE + 390 * 4);            // 384 ints
static constexpr size_t OFF_TMP   = AL(OFF_CCUR + 384 * 4);             // 6*NE int2
static constexpr size_t OFF_SRCW  = AL(OFF_TMP + (size_t)6 * NE * 8);   // 6*PADNE u32

extern "C" void kernel_launch(void* const* d_in, const int* in_sizes, int n_in,
                              void* d_out, int out_size, void* d_ws, size_t ws_size,
                              hipStream_t stream) {
  char* wsb = (char*)d_ws;
  unsigned short* agg = (unsigned short*)(wsb + OFF_AGG);
  unsigned char* hp   = (unsigned char*)(wsb + OFF_HP);
  unsigned short* wbf = (unsigned short*)(wsb + OFF_WBF);
  int* poffs = (int*)(wsb + OFF_POFF);
  int* pends = (int*)(wsb + OFF_PEND);
  int* chist = (int*)(wsb + OFF_CHIST);
  int* cbase = (int*)(wsb + OFF_CBASE);
  int* pbase = (int*)(wsb + OFF_PBASE);
  int* ccur  = (int*)(wsb + OFF_CCUR);
  int2* tmp  = (int2*)(wsb + OFF_TMP);
  unsigned* srcw = (unsigned*)(wsb + OFF_SRCW);
  float* out = (float*)d_out;

  // relation order: l2g, g2l, g2d, d2g, l2d, d2l
  const int base[6] = {3, 8, 13, 18, 23, 28};
  const int ndst[6] = {NGr, NLr, NDr, NGr, NDr, NLr};
  const size_t hpOff[6]  = {HPe_L2G, HPe_G2L, HPe_G2D, HPe_D2G, HPe_L2D, HPe_D2L};

  // merged prep: weight f32->bf16 + coarse dst histogram
  (void)hipMemsetAsync(chist, 0, 384 * 4, stream);
  PrepTab Q; PTab P; NTab N;
  Q.wsrc[0] = (const float*)d_in[6];  Q.wsrc[1] = (const float*)d_in[11];
  Q.wsrc[2] = (const float*)d_in[16]; Q.wsrc[3] = (const float*)d_in[21];
  Q.wsrc[4] = (const float*)d_in[26]; Q.wsrc[5] = (const float*)d_in[31];
  Q.wsrc[6] = (const float*)d_in[33]; Q.wsrc[7] = (const float*)d_in[36];
  Q.wsrc[8] = (const float*)d_in[39];
  for (int r = 0; r < 6; ++r) {
    int sh = (ndst[r] == NGr) ? 9 : (ndst[r] == NLr ? 8 : 7);  // coarse = n>>6
    Q.dst[r] = (const int*)d_in[base[r] + 1];
    Q.shift[r] = sh;
    P.src[r] = (const int*)d_in[base[r]];
    P.dst[r] = (const int*)d_in[base[r] + 1];
    P.w[r]  = (const float*)d_in[base[r] + 2];
    P.shift[r] = sh;
    N.n[r] = ndst[r];
  }
  prep_kernel<<<2304 + 1536, 256, 0, stream>>>(Q, wbf, chist);
  scan384_kernel<<<1, 64, 0, stream>>>(chist, ccur, cbase, pbase, N);

  // partition pass A (coarse)
  partA6_kernel<<<dim3(NE / 1024, 6), 256, 0, stream>>>(P, ccur, tmp);

  // mid: partB (padded fine placement + poffs/pends) OVERLAPPED with transformT
  // type l -> {l2g(0), l2d(4)}, type g -> {g2l(1), g2d(2)}, type d -> {d2g(3), d2l(5)}
  TTy T;
  T.h[0] = (const float*)d_in[0]; T.h[1] = (const float*)d_in[1]; T.h[2] = (const float*)d_in[2];
  T.hpA[0] = hp + hpOff[0]; T.hpB[0] = hp + hpOff[4];
  T.hpA[1] = hp + hpOff[1]; T.hpB[1] = hp + hpOff[2];
  T.hpA[2] = hp + hpOff[3]; T.hpB[2] = hp + hpOff[5];
  T.wA[0] = wbf + 0 * 65536; T.wB[0] = wbf + 4 * 65536;
  T.wA[1] = wbf + 1 * 65536; T.wB[1] = wbf + 2 * 65536;
  T.wA[2] = wbf + 3 * 65536; T.wB[2] = wbf + 5 * 65536;
  T.cum[0] = 0; T.cum[1] = NLr / 64; T.cum[2] = (NLr + NGr) / 64; T.cum[3] = (NLr + NGr + NDr) / 64;
  mid_kernel<<<384 + 896, 256, 0, stream>>>(tmp, cbase, pbase, poffs, pends, srcw, N, T);

  // gather + attention per dest type: l <- {g2l(1), d2l(5)}, g <- {l2g(0), d2g(3)},
  // d <- {g2d(2), l2d(4)}; one 32-lane group per node (padded fp8 rows)
  GATab G;
  const int relA[3] = {1, 0, 2}, relB[3] = {5, 3, 4};
  const int aA[3] = {12, 7, 17}, aB[3] = {32, 22, 27};
  const size_t aggBase[3] = {0, (size_t)NLr * DIM, (size_t)(NLr + NGr) * DIM};
  for (int t = 0; t < 3; ++t) {
    G.hpA[t] = hp + hpOff[relA[t]];
    G.hpB[t] = hp + hpOff[relB[t]];
    G.swA[t] = srcw + (size_t)relA[t] * PADNE;
    G.swB[t] = srcw + (size_t)relB[t] * PADNE;
    G.poA[t] = poffs + relA[t] * HSTRIDE;
    G.peA[t] = pends + relA[t] * HSTRIDE;
    G.poB[t] = poffs + relB[t] * HSTRIDE;
    G.peB[t] = pends + relB[t] * HSTRIDE;
    G.A1[t] = (const float*)d_in[aA[t]];
    G.A2[t] = (const float*)d_in[aB[t]];
    G.agg[t] = agg + aggBase[t];
  }
  G.cum[0] = 0; G.cum[1] = NLr / 8; G.cum[2] = (NLr + NGr) / 8; G.cum[3] = (NLr + NGr + NDr) / 8;
  gatherAtt_kernel<<<G.cum[3], 256, 0, stream>>>(G);

  // fused update, all 3 types in one launch
  FTab F;
  F.h[0] = (const float*)d_in[0]; F.h[1] = (const float*)d_in[1]; F.h[2] = (const float*)d_in[2];
  F.agg[0] = agg + aggBase[0]; F.agg[1] = agg + aggBase[1]; F.agg[2] = agg + aggBase[2];
  F.wbf[0] = wbf + 6 * 65536; F.wbf[1] = wbf + 7 * 65536; F.wbf[2] = wbf + 8 * 65536;
  F.gm[0] = (const float*)d_in[34]; F.bt[0] = (const float*)d_in[35];
  F.gm[1] = (const float*)d_in[37]; F.bt[1] = (const float*)d_in[38];
  F.gm[2] = (const float*)d_in[40]; F.bt[2] = (const float*)d_in[41];
  F.out[0] = out;
  F.out[1] = out + (size_t)NLr * DIM;
  F.out[2] = out + (size_t)(NLr + NGr) * DIM;
  F.cum[0] = 0; F.cum[1] = NLr / 64; F.cum[2] = (NLr + NGr) / 64; F.cum[3] = (NLr + NGr + NDr) / 64;
  fuse3_kernel<<<F.cum[3], 256, 0, stream>>>(F);
}

// Round 22
// 231.499 us; speedup vs baseline: 1.1709x; 1.0066x over previous
//
#include <hip/hip_runtime.h>

#define DIM 256
#define NLr 16384
#define NGr 32768
#define NDr 8192
#define NE  262144
#define PADNE 524288   // padded srcw stride: NE + 8*max_n
#define HSTRIDE 32772  // poffs/pends per-relation stride (16B-aligned)

typedef short bf16x8 __attribute__((ext_vector_type(8)));
typedef float f32x4 __attribute__((ext_vector_type(4)));
typedef float f32x2 __attribute__((ext_vector_type(2)));
typedef unsigned u32x4 __attribute__((ext_vector_type(4)));

__device__ __forceinline__ unsigned short f2bf(float f) {
  unsigned int u = __builtin_bit_cast(unsigned int, f);
  u += 0x7fffu + ((u >> 16) & 1u);
  return (unsigned short)(u >> 16);
}
__device__ __forceinline__ float bf2f(unsigned short b) {
  return __builtin_bit_cast(float, ((unsigned int)b) << 16);
}
__device__ __forceinline__ float bfhi(unsigned int u) {
  return __builtin_bit_cast(float, u & 0xffff0000u);
}

struct NTab { int n[6]; };
struct PrepTab { const float* wsrc[9]; const int* dst[6]; int shift[6]; };
struct PTab { const int* src[6]; const int* dst[6]; const float* w[6]; int shift[6]; };
struct TTy { const float* h[3]; unsigned char* hpA[3]; unsigned char* hpB[3];
             const unsigned short* wA[3]; const unsigned short* wB[3]; int cum[4]; };
struct GATab { const unsigned char* hpA[3]; const unsigned char* hpB[3];
               const unsigned* swA[3]; const unsigned* swB[3];
               const int* poA[3]; const int* peA[3];
               const int* poB[3]; const int* peB[3];
               const float* A1[3]; const float* A2[3];
               unsigned short* agg[3]; int cum[4]; };
struct FTab { const float* h[3]; const unsigned short* agg[3];
              const unsigned short* wbf[3]; const float* gm[3]; const float* bt[3];
              float* out[3]; int cum[4]; };

// ---- merged prep: blocks [0,2304) convert 9 weight mats; [2304,3840) coarse hist ----
__global__ __launch_bounds__(256) void prep_kernel(PrepTab Q, unsigned short* __restrict__ wbf,
                                                   int* __restrict__ chist) {
  const int bid = blockIdx.x, tid = threadIdx.x;
  __shared__ int h[64];
  if (bid < 2304) {
    int m = bid >> 8;
    int i = (bid & 255) * 256 + tid;
    wbf[m * 65536 + i] = f2bf(Q.wsrc[m][i]);
  } else {
    int b2 = bid - 2304;
    int r = b2 >> 8;          // 256 blocks per relation, 1024 edges each
    int blk = b2 & 255;
    if (tid < 64) h[tid] = 0;
    __syncthreads();
    const int* dp = Q.dst[r] + blk * 1024;
    const int sh = Q.shift[r];
#pragma unroll
    for (int k = 0; k < 4; ++k) atomicAdd(&h[dp[k * 256 + tid] >> sh], 1);
    __syncthreads();
    if (tid < 64) { int c = h[tid]; if (c) atomicAdd(&chist[r * 64 + tid], c); }
  }
}

// ---- tiny coarse scan: ccur (partA cursor), cbase (tmp windows), pbase (padded srcw) ----
__global__ void scan384_kernel(const int* __restrict__ chist, int* __restrict__ ccur,
                               int* __restrict__ cbase, int* __restrict__ pbase, NTab N) {
  int r = threadIdx.x;
  if (r < 6) {
    int off = 0, offp = 0;
    int s8 = (N.n[r] >> 6) * 8;   // per-window pad slack
    for (int b = 0; b < 64; ++b) {
      ccur[r * 64 + b] = off;
      cbase[r * 65 + b] = off;
      pbase[r * 65 + b] = offp;
      off += chist[r * 64 + b];
      offp += chist[r * 64 + b] + s8;
    }
    cbase[r * 65 + 64] = off;  // == NE
  }
}

// ---- partition pass A: coarse 64-bucket partition into tmp (dst, packed) ----
__global__ __launch_bounds__(256) void partA6_kernel(PTab P, int* __restrict__ ccur,
                                                     int2* __restrict__ tmp) {
  int r = blockIdx.y;
  const int tid = threadIdx.x;
  __shared__ int hist[64], lbase[64], lcur[64];
  if (tid < 64) { hist[tid] = 0; lcur[tid] = 0; }
  __syncthreads();
  const int ebase = blockIdx.x * 1024;
  const int sh = P.shift[r];
  int dsts[4]; unsigned pk[4]; int bks[4];
#pragma unroll
  for (int k = 0; k < 4; ++k) {
    int e = ebase + k * 256 + tid;
    int d = P.dst[r][e];
    dsts[k] = d;
    pk[k] = (unsigned)P.src[r][e] | ((unsigned)f2bf(P.w[r][e]) << 16);
    bks[k] = d >> sh;
    atomicAdd(&hist[bks[k]], 1);
  }
  __syncthreads();
  if (tid < 64) {
    int c = hist[tid];
    if (c) lbase[tid] = atomicAdd(&ccur[r * 64 + tid], c);
  }
  __syncthreads();
#pragma unroll
  for (int k = 0; k < 4; ++k) {
    int pos = lbase[bks[k]] + atomicAdd(&lcur[bks[k]], 1);
    tmp[(size_t)r * NE + pos] = make_int2(dsts[k], (int)pk[k]);
  }
}

// ---- shared GEMM pieces: 64 rows x (256x256) bf16 MFMA (rounds 6-21 proven) ----
__device__ __forceinline__ void stage_x_f32(const float* __restrict__ g, int r0,
                                            unsigned short* xs, int tid) {
#pragma unroll
  for (int it = 0; it < 16; ++it) {
    int i = it * 256 + tid;
    int row = i >> 6, q = i & 63;
    float4 v = reinterpret_cast<const float4*>(g)[(size_t)(r0 + row) * 64 + q];
    ushort4 b;
    b.x = f2bf(v.x); b.y = f2bf(v.y); b.z = f2bf(v.z); b.w = f2bf(v.w);
    *reinterpret_cast<ushort4*>(&xs[row * 264 + q * 4]) = b;
  }
}

__device__ __forceinline__ void gemm_frag(const unsigned short* xs,
                                          const unsigned short* __restrict__ Wg,
                                          unsigned short* wl, int tid,
                                          f32x4 accv[4][4]) {
  const int wid = tid >> 6, lhi = (tid & 63) >> 4, llo = tid & 15;
  for (int ks = 0; ks < 8; ++ks) {
    const int k0 = ks * 32;
    __syncthreads();  // protects xs (first iter) and wl reads from prev iter
    {
      const uint4* gp = reinterpret_cast<const uint4*>(Wg + (size_t)tid * 256 + k0);
      uint4 a0 = gp[0], a1 = gp[1], a2 = gp[2], a3 = gp[3];
      uint4* lp = reinterpret_cast<uint4*>(wl + tid * 56);
      lp[0] = a0; lp[1] = a1; lp[2] = a2; lp[3] = a3;
    }
    __syncthreads();
    bf16x8 afr[4], bfr[4];
#pragma unroll
    for (int rt = 0; rt < 4; ++rt)
      afr[rt] = *reinterpret_cast<const bf16x8*>(&xs[(rt * 16 + llo) * 264 + k0 + lhi * 8]);
#pragma unroll
    for (int nt = 0; nt < 4; ++nt)
      bfr[nt] = *reinterpret_cast<const bf16x8*>(&wl[(wid * 64 + nt * 16 + llo) * 56 + lhi * 8]);
#pragma unroll
    for (int rt = 0; rt < 4; ++rt)
#pragma unroll
      for (int nt = 0; nt < 4; ++nt)
        accv[rt][nt] = __builtin_amdgcn_mfma_f32_16x16x32_bf16(afr[rt], bfr[nt], accv[rt][nt], 0, 0, 0);
  }
}

// ---- writeout: accv -> fp8 e4m3 bytes (hp row = 256 B) ----
__device__ __forceinline__ void writeout_hp(unsigned char* __restrict__ hp, int r0, int tid,
                                            f32x4 accv[4][4]) {
  const int wid = tid >> 6, lane = tid & 63, lhi = lane >> 4, llo = lane & 15;
#pragma unroll
  for (int rt = 0; rt < 4; ++rt)
#pragma unroll
    for (int nt = 0; nt < 4; ++nt) {
      int col = wid * 64 + nt * 16 + llo;
#pragma unroll
      for (int rg = 0; rg < 4; ++rg) {
        int row = rt * 16 + lhi * 4 + rg;
        int pk = __builtin_amdgcn_cvt_pk_fp8_f32(accv[rt][nt][rg], accv[rt][nt][rg], 0, false);
        hp[(size_t)(r0 + row) * DIM + col] = (unsigned char)(pk & 0xff);
      }
    }
}

// ---- mid kernel: partB (blocks [0,384)) ∥ transformT (blocks [384,1280)) ----
// partB emits PADDED buckets (pend-pstart = ceil(cnt/8)*8, pads zero-filled).
__global__ __launch_bounds__(256) void mid_kernel(const int2* __restrict__ tmp,
                                                  const int* __restrict__ cbase,
                                                  const int* __restrict__ pbase,
                                                  int* __restrict__ poffs,
                                                  int* __restrict__ pends,
                                                  unsigned* __restrict__ srcw,
                                                  NTab N, TTy T) {
  __shared__ union alignas(16) SM {
    struct { unsigned short xs[64 * 264]; unsigned short wl[256 * 56]; } t;
    struct { int hist[512]; int part[256]; int pend[512]; } p;
  } sm;
  const int bid = blockIdx.x, tid = threadIdx.x;

  if (bid < 384) {
    // ---------------- partB path (padded placement) ----------------
    int r = bid >> 6, b = bid & 63;
    const int n = N.n[r], s = n >> 6;
    const int dbase = b * s;
    int* hist = sm.p.hist;
    int* part = sm.p.part;
    int* pendL = sm.p.pend;
    for (int i = tid; i < s; i += 256) hist[i] = 0;
    __syncthreads();
    const int wbeg = cbase[r * 65 + b], wend = cbase[r * 65 + b + 1];
    const int2* __restrict__ tr = tmp + (size_t)r * NE;
    for (int i = wbeg + tid; i < wend; i += 256)
      atomicAdd(&hist[tr[i].x - dbase], 1);
    __syncthreads();
    const int per = (s > 256) ? 2 : 1;
    const int base = tid * per;
    int pv[2];
    int mysum = 0;
#pragma unroll
    for (int j = 0; j < 2; ++j) {
      int idx = base + j;
      int cnt = (j < per && idx < s) ? hist[idx] : 0;
      pv[j] = (cnt + 7) & ~7;          // padded bucket length
      mysum += pv[j];
    }
    part[tid] = mysum;
    __syncthreads();
    for (int off = 1; off < 256; off <<= 1) {
      int v = (tid >= off) ? part[tid - off] : 0;
      __syncthreads();
      part[tid] += v;
      __syncthreads();
    }
    int run = part[tid] - mysum + pbase[r * 65 + b];
#pragma unroll
    for (int j = 0; j < 2; ++j) {
      int idx = base + j;
      if (j < per && idx < s) {
        hist[idx] = run;                               // live cursor (real entries)
        pendL[idx] = run + pv[j];
        poffs[r * HSTRIDE + dbase + idx] = run;        // padded start
        pends[r * HSTRIDE + dbase + idx] = run + pv[j];// padded end
        run += pv[j];
      }
    }
    __syncthreads();
    unsigned* __restrict__ swr = srcw + (size_t)r * PADNE;
    for (int i = wbeg + tid; i < wend; i += 256) {
      int2 e = tr[i];
      int pos = atomicAdd(&hist[e.x - dbase], 1);
      swr[pos] = (unsigned)e.y;
    }
    __syncthreads();
    // zero-fill pad slots (src=0, w=+0.0 -> exact no-op in gather)
    for (int i = tid; i < s; i += 256)
      for (int p = hist[i]; p < pendL[i]; ++p) swr[p] = 0u;
  } else {
    // ---------------- transformT path (fp8 writeout) ----------------
    const int bx = bid - 384;
    int t = 0;
#pragma unroll
    for (int k = 1; k < 3; ++k) t += (bx >= T.cum[k]);
    const int r0 = (bx - T.cum[t]) * 64;

    stage_x_f32(T.h[t], r0, sm.t.xs, tid);

    f32x4 accv[4][4];
#pragma unroll
    for (int a = 0; a < 4; ++a)
#pragma unroll
      for (int b2 = 0; b2 < 4; ++b2) accv[a][b2] = {0.f, 0.f, 0.f, 0.f};
    gemm_frag(sm.t.xs, T.wA[t], sm.t.wl, tid, accv);
    writeout_hp(T.hpA[t], r0, tid, accv);

#pragma unroll
    for (int a = 0; a < 4; ++a)
#pragma unroll
      for (int b2 = 0; b2 < 4; ++b2) accv[a][b2] = {0.f, 0.f, 0.f, 0.f};
    gemm_frag(sm.t.xs, T.wB[t], sm.t.wl, tid, accv);  // first barrier inside protects wl reuse
    writeout_hp(T.hpB[t], r0, tid, accv);
  }
}

// ---- bucket walk: fp8 rows, f32x2 math, guard-free (padded %8 -> %4), 32-lane group ----
__device__ __forceinline__ void bucket_msg(const unsigned* __restrict__ sw,
                                           const unsigned char* __restrict__ hp,
                                           int beg, int end, int c8,
                                           float& m0, float& m1, float& m2, float& m3,
                                           float& m4, float& m5, float& m6, float& m7) {
  f32x2 a01 = {0.f, 0.f}, a23 = {0.f, 0.f}, a45 = {0.f, 0.f}, a67 = {0.f, 0.f};
  float degw = 0.f;
  const int boff = c8 * 8;
  for (int j = beg; j < end; j += 4) {
    unsigned e0 = sw[j + 0], e1 = sw[j + 1], e2 = sw[j + 2], e3 = sw[j + 3];
    float w0 = bfhi(e0), w1 = bfhi(e1), w2 = bfhi(e2), w3 = bfhi(e3);
    uint2 x0 = *reinterpret_cast<const uint2*>(hp + (size_t)(e0 & 0xffff) * DIM + boff);
    uint2 x1 = *reinterpret_cast<const uint2*>(hp + (size_t)(e1 & 0xffff) * DIM + boff);
    uint2 x2 = *reinterpret_cast<const uint2*>(hp + (size_t)(e2 & 0xffff) * DIM + boff);
    uint2 x3 = *reinterpret_cast<const uint2*>(hp + (size_t)(e3 & 0xffff) * DIM + boff);
    degw += (w0 + w1) + (w2 + w3);
    f32x2 wv0 = {w0, w0}, wv1 = {w1, w1}, wv2 = {w2, w2}, wv3 = {w3, w3};
    a01 += wv0 * __builtin_amdgcn_cvt_pk_f32_fp8(x0.x, false);
    a23 += wv0 * __builtin_amdgcn_cvt_pk_f32_fp8(x0.x, true);
    a45 += wv0 * __builtin_amdgcn_cvt_pk_f32_fp8(x0.y, false);
    a67 += wv0 * __builtin_amdgcn_cvt_pk_f32_fp8(x0.y, true);
    a01 += wv1 * __builtin_amdgcn_cvt_pk_f32_fp8(x1.x, false);
    a23 += wv1 * __builtin_amdgcn_cvt_pk_f32_fp8(x1.x, true);
    a45 += wv1 * __builtin_amdgcn_cvt_pk_f32_fp8(x1.y, false);
    a67 += wv1 * __builtin_amdgcn_cvt_pk_f32_fp8(x1.y, true);
    a01 += wv2 * __builtin_amdgcn_cvt_pk_f32_fp8(x2.x, false);
    a23 += wv2 * __builtin_amdgcn_cvt_pk_f32_fp8(x2.x, true);
    a45 += wv2 * __builtin_amdgcn_cvt_pk_f32_fp8(x2.y, false);
    a67 += wv2 * __builtin_amdgcn_cvt_pk_f32_fp8(x2.y, true);
    a01 += wv3 * __builtin_amdgcn_cvt_pk_f32_fp8(x3.x, false);
    a23 += wv3 * __builtin_amdgcn_cvt_pk_f32_fp8(x3.x, true);
    a45 += wv3 * __builtin_amdgcn_cvt_pk_f32_fp8(x3.y, false);
    a67 += wv3 * __builtin_amdgcn_cvt_pk_f32_fp8(x3.y, true);
  }
  float inv = (degw == 0.f) ? 1.f : 1.f / degw;
  m0 = a01.x * inv; m1 = a01.y * inv; m2 = a23.x * inv; m3 = a23.y * inv;
  m4 = a45.x * inv; m5 = a45.y * inv; m6 = a67.x * inv; m7 = a67.y * inv;
}

// ---- gather + relation attention: agg[node] = c1*mA + c2*mB (bf16) ----
// one 32-lane group per node (8 nodes / 256-block); group holds all 256 dims.
__global__ __launch_bounds__(256) void gatherAtt_kernel(GATab T) {
  const int bx = blockIdx.x;
  int t = 0;
#pragma unroll
  for (int k = 1; k < 3; ++k) t += (bx >= T.cum[k]);
  const int node = (bx - T.cum[t]) * 8 + (threadIdx.x >> 5);
  const int c8 = threadIdx.x & 31;

  float mA0, mA1, mA2, mA3, mA4, mA5, mA6, mA7;
  float mB0, mB1, mB2, mB3, mB4, mB5, mB6, mB7;
  bucket_msg(T.swA[t], T.hpA[t], T.poA[t][node], T.peA[t][node], c8,
             mA0, mA1, mA2, mA3, mA4, mA5, mA6, mA7);
  bucket_msg(T.swB[t], T.hpB[t], T.poB[t][node], T.peB[t][node], c8,
             mB0, mB1, mB2, mB3, mB4, mB5, mB6, mB7);

  // attention: scores via in-register dots + intra-group shfl reduce, then softmax
  const float4* A1v = reinterpret_cast<const float4*>(T.A1[t]);  // [4][64] float4
  const float4* A2v = reinterpret_cast<const float4*>(T.A2[t]);
  float c1 = 0.f, c2 = 0.f;
#pragma unroll
  for (int hh = 0; hh < 4; ++hh) {
    float4 qa = A1v[hh * 64 + c8 * 2], qb = A1v[hh * 64 + c8 * 2 + 1];
    float4 ra = A2v[hh * 64 + c8 * 2], rb = A2v[hh * 64 + c8 * 2 + 1];
    float sA = mA0 * qa.x + mA1 * qa.y + mA2 * qa.z + mA3 * qa.w
             + mA4 * qb.x + mA5 * qb.y + mA6 * qb.z + mA7 * qb.w;
    float sB = mB0 * ra.x + mB1 * ra.y + mB2 * ra.z + mB3 * ra.w
             + mB4 * rb.x + mB5 * rb.y + mB6 * rb.z + mB7 * rb.w;
#pragma unroll
    for (int o = 1; o <= 16; o <<= 1) { sA += __shfl_xor(sA, o); sB += __shfl_xor(sB, o); }
    // softmax over the 2 relations; scale = 1/(sqrt(256)*0.5) = 0.125
    float s1 = sA * 0.125f, s2 = sB * 0.125f;
    float mx = fmaxf(s1, s2);
    float e1 = __expf(s1 - mx), e2 = __expf(s2 - mx);
    float inv = 1.f / (e1 + e2);
    c1 += e1 * inv; c2 += e2 * inv;
  }
  c1 *= 0.25f; c2 *= 0.25f;  // mean over H=4 heads

  u32x4 o;
  o.x = (unsigned)f2bf(c1 * mA0 + c2 * mB0) | ((unsigned)f2bf(c1 * mA1 + c2 * mB1) << 16);
  o.y = (unsigned)f2bf(c1 * mA2 + c2 * mB2) | ((unsigned)f2bf(c1 * mA3 + c2 * mB3) << 16);
  o.z = (unsigned)f2bf(c1 * mA4 + c2 * mB4) | ((unsigned)f2bf(c1 * mA5 + c2 * mB5) << 16);
  o.w = (unsigned)f2bf(c1 * mA6 + c2 * mB6) | ((unsigned)f2bf(c1 * mA7 + c2 * mB7) << 16);
  __builtin_nontemporal_store(o, reinterpret_cast<u32x4*>(T.agg[t]) + (size_t)node * 32 + c8);
}

// ---- all 3 types merged: self-GEMM + agg + residual(h in regs) + LN + leaky ----
// residual h kept in registers from staging (bf16); epilogue rows = it*4 + wid
__global__ __launch_bounds__(256) void fuse3_kernel(FTab F) {
  __shared__ alignas(16) union SM {
    struct { unsigned short x[64 * 264]; unsigned short w[256 * 56]; } g;
    unsigned short s[64 * 260];  // self result, bf16
  } ov;
  __shared__ float sgb[512];
  const int tid = threadIdx.x;
  const int bx = blockIdx.x;
  int t = 0;
#pragma unroll
  for (int k = 1; k < 3; ++k) t += (bx >= F.cum[k]);
  const int r0 = (bx - F.cum[t]) * 64;
  const float* __restrict__ h = F.h[t];
  const unsigned short* __restrict__ agg = F.agg[t];

  // stage h -> LDS (bf16), keeping each thread's fragments in registers:
  // thread tid holds rows it*4 + (tid>>6), col-quad (tid&63), it = 0..15
  ushort4 hreg[16];
#pragma unroll
  for (int it = 0; it < 16; ++it) {
    int i = it * 256 + tid;
    int row = i >> 6, q = i & 63;
    float4 v = reinterpret_cast<const float4*>(h)[(size_t)(r0 + row) * 64 + q];
    ushort4 b;
    b.x = f2bf(v.x); b.y = f2bf(v.y); b.z = f2bf(v.z); b.w = f2bf(v.w);
    hreg[it] = b;
    *reinterpret_cast<ushort4*>(&ov.g.x[row * 264 + q * 4]) = b;
  }
  for (int i = tid; i < 512; i += 256) sgb[i] = (i < 256) ? F.gm[t][i] : F.bt[t][i - 256];

  f32x4 accv[4][4];
#pragma unroll
  for (int a = 0; a < 4; ++a)
#pragma unroll
    for (int b = 0; b < 4; ++b) accv[a][b] = {0.f, 0.f, 0.f, 0.f};

  gemm_frag(ov.g.x, F.wbf[t], ov.g.w, tid, accv);

  const int wid = tid >> 6, lane = tid & 63, lhi = lane >> 4, llo = lane & 15;
  __syncthreads();  // all MFMA LDS reads done before overlaying ov.s
#pragma unroll
  for (int rt = 0; rt < 4; ++rt)
#pragma unroll
    for (int nt = 0; nt < 4; ++nt) {
      int col = wid * 64 + nt * 16 + llo;
#pragma unroll
      for (int rg = 0; rg < 4; ++rg)
        ov.s[(rt * 16 + lhi * 4 + rg) * 260 + col] = f2bf(accv[rt][nt][rg]);
    }
  __syncthreads();

  // epilogue: wave wid handles rows {it*4 + wid}; lane owns 4 dims (matches hreg)
  const int d0 = lane * 4;
  const float4 g4 = *reinterpret_cast<const float4*>(&sgb[d0]);
  const float4 b4 = *reinterpret_cast<const float4*>(&sgb[256 + d0]);
  float* __restrict__ outp = F.out[t];

#pragma unroll
  for (int it = 0; it < 16; ++it) {
    int row = it * 4 + wid;
    size_t gb = (size_t)(r0 + row) * DIM + d0;
    ushort4 ab = *reinterpret_cast<const ushort4*>(agg + gb);
    float4 av = {bf2f(ab.x), bf2f(ab.y), bf2f(ab.z), bf2f(ab.w)};
    float4 hvv = {bf2f(hreg[it].x), bf2f(hreg[it].y), bf2f(hreg[it].z), bf2f(hreg[it].w)};
    ushort4 sb = *reinterpret_cast<const ushort4*>(&ov.s[row * 260 + d0]);
    float4 sv = {bf2f(sb.x), bf2f(sb.y), bf2f(sb.z), bf2f(sb.w)};

    float4 u;
    u.x = sv.x + av.x + hvv.x;
    u.y = sv.y + av.y + hvv.y;
    u.z = sv.z + av.z + hvv.z;
    u.w = sv.w + av.w + hvv.w;

    float s1v = u.x + u.y + u.z + u.w;
    float s2v = u.x * u.x + u.y * u.y + u.z * u.z + u.w * u.w;
#pragma unroll
    for (int o = 1; o < 64; o <<= 1) { s1v += __shfl_xor(s1v, o); s2v += __shfl_xor(s2v, o); }
    float mu = s1v * (1.f / 256.f);
    float var = s2v * (1.f / 256.f) - mu * mu;
    float rstd = rsqrtf(var + 1e-5f);

    f32x4 y;
    y.x = (u.x - mu) * rstd * g4.x + b4.x;
    y.y = (u.y - mu) * rstd * g4.y + b4.y;
    y.z = (u.z - mu) * rstd * g4.z + b4.z;
    y.w = (u.w - mu) * rstd * g4.w + b4.w;
    y.x = fmaxf(y.x, 0.01f * y.x);
    y.y = fmaxf(y.y, 0.01f * y.y);
    y.z = fmaxf(y.z, 0.01f * y.z);
    y.w = fmaxf(y.w, 0.01f * y.w);
    __builtin_nontemporal_store(y, reinterpret_cast<f32x4*>(outp + gb));
  }
}

// ---- workspace layout (bytes); ~88 MB (< proven ~139 MB) ----
static constexpr size_t AL(size_t x) { return (x + 255) & ~size_t(255); }
// aggregated messages (bf16), one row per node, type-major l|g|d
static constexpr size_t AGG_TOT = (size_t)(NLr + NGr + NDr) * DIM;      // ushorts
// transformed embeddings (fp8, 1 byte/elem), all 6 relations, sized by SRC rows
static constexpr size_t HPe_L2G = 0;                                    // NLr rows
static constexpr size_t HPe_G2L = HPe_L2G + (size_t)NLr * DIM;          // NGr
static constexpr size_t HPe_G2D = HPe_G2L + (size_t)NGr * DIM;          // NGr
static constexpr size_t HPe_D2G = HPe_G2D + (size_t)NGr * DIM;          // NDr
static constexpr size_t HPe_L2D = HPe_D2G + (size_t)NDr * DIM;          // NLr
static constexpr size_t HPe_D2L = HPe_L2D + (size_t)NLr * DIM;          // NDr
static constexpr size_t HP_TOT  = HPe_D2L + (size_t)NDr * DIM;          // bytes
static constexpr size_t OFF_AGG   = 0;
static constexpr size_t OFF_HP    = AL(OFF_AGG + AGG_TOT * 2);
static constexpr size_t OFF_WBF   = AL(OFF_HP + HP_TOT);
static constexpr size_t OFF_POFF  = AL(OFF_WBF + 9 * 65536 * 2);        // 6*HSTRIDE ints
static constexpr size_t OFF_PEND  = AL(OFF_POFF + 6 * HSTRIDE * 4);     // 6*HSTRIDE ints
static constexpr size_t OFF_CHIST = AL(OFF_PEND + 6 * HSTRIDE * 4);     // 384 ints
static constexpr size_t OFF_CBASE = AL(OFF_CHIST + 384 * 4);            // 6*65 ints
static constexpr size_t OFF_PBASE = AL(OFF_CBASE + 390 * 4);            // 6*65 ints
static constexpr size_t OFF_CCUR  = AL(OFF_PBASE + 390 * 4);            // 384 ints
static constexpr size_t OFF_TMP   = AL(OFF_CCUR + 384 * 4);             // 6*NE int2
static constexpr size_t OFF_SRCW  = AL(OFF_TMP + (size_t)6 * NE * 8);   // 6*PADNE u32

extern "C" void kernel_launch(void* const* d_in, const int* in_sizes, int n_in,
                              void* d_out, int out_size, void* d_ws, size_t ws_size,
                              hipStream_t stream) {
  char* wsb = (char*)d_ws;
  unsigned short* agg = (unsigned short*)(wsb + OFF_AGG);
  unsigned char* hp   = (unsigned char*)(wsb + OFF_HP);
  unsigned short* wbf = (unsigned short*)(wsb + OFF_WBF);
  int* poffs = (int*)(wsb + OFF_POFF);
  int* pends = (int*)(wsb + OFF_PEND);
  int* chist = (int*)(wsb + OFF_CHIST);
  int* cbase = (int*)(wsb + OFF_CBASE);
  int* pbase = (int*)(wsb + OFF_PBASE);
  int* ccur  = (int*)(wsb + OFF_CCUR);
  int2* tmp  = (int2*)(wsb + OFF_TMP);
  unsigned* srcw = (unsigned*)(wsb + OFF_SRCW);
  float* out = (float*)d_out;

  // relation order: l2g, g2l, g2d, d2g, l2d, d2l
  const int base[6] = {3, 8, 13, 18, 23, 28};
  const int ndst[6] = {NGr, NLr, NDr, NGr, NDr, NLr};
  const size_t hpOff[6]  = {HPe_L2G, HPe_G2L, HPe_G2D, HPe_D2G, HPe_L2D, HPe_D2L};

  // merged prep: weight f32->bf16 + coarse dst histogram
  (void)hipMemsetAsync(chist, 0, 384 * 4, stream);
  PrepTab Q; PTab P; NTab N;
  Q.wsrc[0] = (const float*)d_in[6];  Q.wsrc[1] = (const float*)d_in[11];
  Q.wsrc[2] = (const float*)d_in[16]; Q.wsrc[3] = (const float*)d_in[21];
  Q.wsrc[4] = (const float*)d_in[26]; Q.wsrc[5] = (const float*)d_in[31];
  Q.wsrc[6] = (const float*)d_in[33]; Q.wsrc[7] = (const float*)d_in[36];
  Q.wsrc[8] = (const float*)d_in[39];
  for (int r = 0; r < 6; ++r) {
    int sh = (ndst[r] == NGr) ? 9 : (ndst[r] == NLr ? 8 : 7);  // coarse = n>>6
    Q.dst[r] = (const int*)d_in[base[r] + 1];
    Q.shift[r] = sh;
    P.src[r] = (const int*)d_in[base[r]];
    P.dst[r] = (const int*)d_in[base[r] + 1];
    P.w[r]  = (const float*)d_in[base[r] + 2];
    P.shift[r] = sh;
    N.n[r] = ndst[r];
  }
  prep_kernel<<<2304 + 1536, 256, 0, stream>>>(Q, wbf, chist);
  scan384_kernel<<<1, 64, 0, stream>>>(chist, ccur, cbase, pbase, N);

  // partition pass A (coarse)
  partA6_kernel<<<dim3(NE / 1024, 6), 256, 0, stream>>>(P, ccur, tmp);

  // mid: partB (padded fine placement + poffs/pends) OVERLAPPED with transformT
  // type l -> {l2g(0), l2d(4)}, type g -> {g2l(1), g2d(2)}, type d -> {d2g(3), d2l(5)}
  TTy T;
  T.h[0] = (const float*)d_in[0]; T.h[1] = (const float*)d_in[1]; T.h[2] = (const float*)d_in[2];
  T.hpA[0] = hp + hpOff[0]; T.hpB[0] = hp + hpOff[4];
  T.hpA[1] = hp + hpOff[1]; T.hpB[1] = hp + hpOff[2];
  T.hpA[2] = hp + hpOff[3]; T.hpB[2] = hp + hpOff[5];
  T.wA[0] = wbf + 0 * 65536; T.wB[0] = wbf + 4 * 65536;
  T.wA[1] = wbf + 1 * 65536; T.wB[1] = wbf + 2 * 65536;
  T.wA[2] = wbf + 3 * 65536; T.wB[2] = wbf + 5 * 65536;
  T.cum[0] = 0; T.cum[1] = NLr / 64; T.cum[2] = (NLr + NGr) / 64; T.cum[3] = (NLr + NGr + NDr) / 64;
  mid_kernel<<<384 + 896, 256, 0, stream>>>(tmp, cbase, pbase, poffs, pends, srcw, N, T);

  // gather + attention per dest type: l <- {g2l(1), d2l(5)}, g <- {l2g(0), d2g(3)},
  // d <- {g2d(2), l2d(4)}; one 32-lane group per node (padded fp8 rows)
  GATab G;
  const int relA[3] = {1, 0, 2}, relB[3] = {5, 3, 4};
  const int aA[3] = {12, 7, 17}, aB[3] = {32, 22, 27};
  const size_t aggBase[3] = {0, (size_t)NLr * DIM, (size_t)(NLr + NGr) * DIM};
  for (int t = 0; t < 3; ++t) {
    G.hpA[t] = hp + hpOff[relA[t]];
    G.hpB[t] = hp + hpOff[relB[t]];
    G.swA[t] = srcw + (size_t)relA[t] * PADNE;
    G.swB[t] = srcw + (size_t)relB[t] * PADNE;
    G.poA[t] = poffs + relA[t] * HSTRIDE;
    G.peA[t] = pends + relA[t] * HSTRIDE;
    G.poB[t] = poffs + relB[t] * HSTRIDE;
    G.peB[t] = pends + relB[t] * HSTRIDE;
    G.A1[t] = (const float*)d_in[aA[t]];
    G.A2[t] = (const float*)d_in[aB[t]];
    G.agg[t] = agg + aggBase[t];
  }
  G.cum[0] = 0; G.cum[1] = NLr / 8; G.cum[2] = (NLr + NGr) / 8; G.cum[3] = (NLr + NGr + NDr) / 8;
  gatherAtt_kernel<<<G.cum[3], 256, 0, stream>>>(G);

  // fused update, all 3 types in one launch
  FTab F;
  F.h[0] = (const float*)d_in[0]; F.h[1] = (const float*)d_in[1]; F.h[2] = (const float*)d_in[2];
  F.agg[0] = agg + aggBase[0]; F.agg[1] = agg + aggBase[1]; F.agg[2] = agg + aggBase[2];
  F.wbf[0] = wbf + 6 * 65536; F.wbf[1] = wbf + 7 * 65536; F.wbf[2] = wbf + 8 * 65536;
  F.gm[0] = (const float*)d_in[34]; F.bt[0] = (const float*)d_in[35];
  F.gm[1] = (const float*)d_in[37]; F.bt[1] = (const float*)d_in[38];
  F.gm[2] = (const float*)d_in[40]; F.bt[2] = (const float*)d_in[41];
  F.out[0] = out;
  F.out[1] = out + (size_t)NLr * DIM;
  F.out[2] = out + (size_t)(NLr + NGr) * DIM;
  F.cum[0] = 0; F.cum[1] = NLr / 64; F.cum[2] = (NLr + NGr) / 64; F.cum[3] = (NLr + NGr + NDr) / 64;
  fuse3_kernel<<<F.cum[3], 256, 0, stream>>>(F);
}